// Round 3
// baseline (2425.657 us; speedup 1.0000x reference)
//
#include <hip/hip_runtime.h>

typedef unsigned short u16;
typedef short s8v __attribute__((ext_vector_type(8)));
typedef float f4v __attribute__((ext_vector_type(4)));

__device__ __forceinline__ float bf2f(u16 s) {
  unsigned u = ((unsigned)s) << 16;
  return __builtin_bit_cast(float, u);
}
__device__ __forceinline__ u16 f2bf(float f) {
  unsigned u = __builtin_bit_cast(unsigned, f);
  unsigned r = u + 0x7fffu + ((u >> 16) & 1u);  // RNE (no NaN here)
  return (u16)(r >> 16);
}
__device__ __forceinline__ s8v load8bf(const u16* p) {
  return __builtin_bit_cast(s8v, *(const uint4*)p);
}
__device__ __forceinline__ f4v mfma16(s8v a, s8v b, f4v c) {
  return __builtin_amdgcn_mfma_f32_16x16x32_bf16(a, b, c, 0, 0, 0);
}
// 8 consecutive f32 -> bf16 hi + bf16 lo fragments (split precision)
__device__ __forceinline__ void cvt8(const float* p, s8v& hi, s8v& lo) {
  float4 x0 = ((const float4*)p)[0];
  float4 x1 = ((const float4*)p)[1];
  float v[8] = {x0.x, x0.y, x0.z, x0.w, x1.x, x1.y, x1.z, x1.w};
  union { s8v v; u16 a[8]; } H, L;
#pragma unroll
  for (int i = 0; i < 8; ++i) {
    u16 h = f2bf(v[i]);
    H.a[i] = h;
    L.a[i] = f2bf(v[i] - bf2f(h));
  }
  hi = H.v;
  lo = L.v;
}
// tanh(x) = 1 - 2/(1+e^{2x}) via hw exp2/rcp (~1e-6 abs err)
__device__ __forceinline__ float fast_tanh(float x) {
  float t = __builtin_amdgcn_exp2f(x * 2.885390081777927f);
  return 1.f - 2.f * __builtin_amdgcn_rcpf(t + 1.f);
}
__device__ __forceinline__ float fast_sigmoid(float x) {
  float t = __builtin_amdgcn_exp2f(x * -1.4426950408889634f);
  return __builtin_amdgcn_rcpf(1.f + t);
}

// ---------------------------------------------------------------------------
// Prep: transpose g_Whh{0,1} -> f32 [k][j]; e-weights -> bf16; GEMM weights ->
// bf16 hi/lo split pairs.
// ---------------------------------------------------------------------------
__global__ void k_prep(const float* __restrict__ W0, const float* __restrict__ W1,
                       float* __restrict__ Wt0, float* __restrict__ Wt1,
                       const float* __restrict__ E0, const float* __restrict__ E1,
                       const float* __restrict__ E2, u16* __restrict__ B0,
                       u16* __restrict__ B1, u16* __restrict__ B2,
                       const float* __restrict__ gW0, u16* __restrict__ gw0hi,
                       u16* __restrict__ gw0lo, const float* __restrict__ gW1,
                       u16* __restrict__ gw1hi, u16* __restrict__ gw1lo,
                       const float* __restrict__ hW, u16* __restrict__ hWhi,
                       u16* __restrict__ hWlo, const float* __restrict__ dW,
                       u16* __restrict__ dWhi, u16* __restrict__ dWlo) {
  int t = blockIdx.x * 256 + threadIdx.x;  // 589824 total
  if (t < 131072) {
    int layer = t >> 16;
    int idx = t & 65535;
    int k = idx >> 8, j = idx & 255;
    const float* W = layer ? W1 : W0;
    float* Wt = layer ? Wt1 : Wt0;
    Wt[k * 256 + j] = W[j * 256 + k];
  } else if (t < 327680) {
    int c = t - 131072;
    int which = c >> 16;
    int idx = c & 65535;
    const float* src = which == 0 ? E0 : (which == 1 ? E1 : E2);
    u16* dst = which == 0 ? B0 : (which == 1 ? B1 : B2);
    dst[idx] = f2bf(src[idx]);
  } else {
    const float* src;
    u16 *dhi, *dlo;
    int idx;
    if (t < 458752) { idx = t - 327680; src = gW0; dhi = gw0hi; dlo = gw0lo; }
    else if (t < 524288) { idx = t - 458752; src = gW1; dhi = gw1hi; dlo = gw1lo; }
    else if (t < 557056) { idx = t - 524288; src = hW; dhi = hWhi; dlo = hWlo; }
    else { idx = t - 557056; src = dW; dhi = dWhi; dlo = dWlo; }
    float v = src[idx];
    u16 h = f2bf(v);
    dhi[idx] = h;
    dlo[idx] = f2bf(v - bf2f(h));
  }
}

// ---------------------------------------------------------------------------
// xw0 = X @ g_Wih0^T + bih0 + bhh0 (split-bf16, pre-split W). grid (128,4)x256.
// ---------------------------------------------------------------------------
__launch_bounds__(256)
__global__ void k_xw0(const float* __restrict__ input, const float* __restrict__ sentinel,
                      const u16* __restrict__ Whi, const u16* __restrict__ Wlo,
                      const float* __restrict__ b1, const float* __restrict__ b2,
                      float* __restrict__ outxw) {
  const int l = threadIdx.x & 63;
  const int wv = threadIdx.x >> 6;
  const int l15 = l & 15, q = l >> 4;
  const int row0 = blockIdx.x * 64 + wv * 16;
  const int col0 = blockIdx.y * 64;
  int row = row0 + l15;
  int s = row & 511, b = row >> 9;
  const float* aptr = (s == 0) ? sentinel : input + (((size_t)(b * 511 + s - 1)) << 9);
  f4v acc[4];
#pragma unroll
  for (int i = 0; i < 4; ++i) acc[i] = (f4v){0.f, 0.f, 0.f, 0.f};
#pragma unroll
  for (int kt = 0; kt < 16; ++kt) {
    int k0 = kt * 32 + q * 8;
    s8v ah, al;
    cvt8(aptr + k0, ah, al);
#pragma unroll
    for (int nt = 0; nt < 4; ++nt) {
      int j = col0 + nt * 16 + l15;
      s8v wh = load8bf(Whi + ((size_t)j << 9) + k0);
      s8v wl = load8bf(Wlo + ((size_t)j << 9) + k0);
      acc[nt] = mfma16(ah, wh, acc[nt]);
      acc[nt] = mfma16(al, wh, acc[nt]);
      acc[nt] = mfma16(ah, wl, acc[nt]);
    }
  }
#pragma unroll
  for (int nt = 0; nt < 4; ++nt) {
    int col = col0 + nt * 16 + l15;
    float bias = b1[col] + b2[col];
#pragma unroll
    for (int r = 0; r < 4; ++r) {
      int rr = row0 + q * 4 + r;
      outxw[((size_t)rr << 8) + col] = acc[nt][r] + bias;
    }
  }
}

// ---------------------------------------------------------------------------
// Generic split-bf16 C = act(A @ W^T + b1 (+b2)); pre-split W hi/lo.
// act=0: identity; act=1: elu. grid (N/64, J/64) x 256.
// ---------------------------------------------------------------------------
__launch_bounds__(256)
__global__ void k_gemm(const float* __restrict__ A, const u16* __restrict__ Whi,
                       const u16* __restrict__ Wlo, const float* __restrict__ b1,
                       const float* __restrict__ b2, float* __restrict__ outf,
                       int K, int J, int act) {
  const int l = threadIdx.x & 63;
  const int wv = threadIdx.x >> 6;
  const int l15 = l & 15, q = l >> 4;
  const int row0 = blockIdx.x * 64 + wv * 16;
  const int col0 = blockIdx.y * 64;
  const float* aptr = A + (size_t)(row0 + l15) * K;
  f4v acc[4];
#pragma unroll
  for (int i = 0; i < 4; ++i) acc[i] = (f4v){0.f, 0.f, 0.f, 0.f};
  const int nkt = K >> 5;
  for (int kt = 0; kt < nkt; ++kt) {
    int k0 = kt * 32 + q * 8;
    s8v ah, al;
    cvt8(aptr + k0, ah, al);
#pragma unroll
    for (int nt = 0; nt < 4; ++nt) {
      int j = col0 + nt * 16 + l15;
      s8v wh = load8bf(Whi + (size_t)j * K + k0);
      s8v wl = load8bf(Wlo + (size_t)j * K + k0);
      acc[nt] = mfma16(ah, wh, acc[nt]);
      acc[nt] = mfma16(al, wh, acc[nt]);
      acc[nt] = mfma16(ah, wl, acc[nt]);
    }
  }
#pragma unroll
  for (int nt = 0; nt < 4; ++nt) {
    int col = col0 + nt * 16 + l15;
    float bias = b1[col] + (b2 ? b2[col] : 0.f);
#pragma unroll
    for (int r = 0; r < 4; ++r) {
      int rr = row0 + q * 4 + r;
      float v = acc[nt][r] + bias;
      if (act) v = v > 0.f ? v : (__builtin_amdgcn_exp2f(v * 1.4426950408889634f) - 1.f);
      outf[(size_t)rr * J + col] = v;
    }
  }
}

// ---------------------------------------------------------------------------
// Sequential RNN scan, one wg per batch row, pure f32. 512 threads:
// tid = p*256+j (p in {0,1}), thread holds 128 Wt values in VGPRs.
// xw prefetched one step ahead; mask staged in LDS; fast tanh.
// ---------------------------------------------------------------------------
__launch_bounds__(512)
__global__ void k_scan(const float* __restrict__ xw, const float* __restrict__ Wt,
                       float* __restrict__ outf, const int* __restrict__ mask) {
  __shared__ __align__(16) float hcur[256];
  __shared__ float partials[512];
  __shared__ float smask[512];
  const int tid = threadIdx.x;
  const int p = tid >> 8, j = tid & 255;
  const int b = blockIdx.x;
  float w[128];
#pragma unroll
  for (int i = 0; i < 128; ++i) w[i] = Wt[(p * 128 + i) * 256 + j];
  if (tid < 256) hcur[tid] = 0.f;
  smask[tid] = (tid == 0) ? 1.f : (mask ? (float)mask[b * 511 + tid - 1] : 1.f);
  __syncthreads();
  const float4* hc4 = (const float4*)hcur;
  const size_t base = ((size_t)b << 9);
  float xwv = (tid < 256) ? xw[(base << 8) + j] : 0.f;
  for (int s = 0; s < 512; ++s) {
    float xwn = (tid < 256 && s < 511) ? xw[((base + s + 1) << 8) + j] : 0.f;
    float s0 = 0.f, s1 = 0.f, s2 = 0.f, s3 = 0.f;
#pragma unroll
    for (int i = 0; i < 32; ++i) {
      float4 h4 = hc4[(p << 5) + i];
      s0 = __builtin_fmaf(h4.x, w[4 * i + 0], s0);
      s1 = __builtin_fmaf(h4.y, w[4 * i + 1], s1);
      s2 = __builtin_fmaf(h4.z, w[4 * i + 2], s2);
      s3 = __builtin_fmaf(h4.w, w[4 * i + 3], s3);
    }
    partials[tid] = (s0 + s1) + (s2 + s3);
    __syncthreads();
    if (tid < 256) {
      float v = partials[j] + partials[256 + j] + xwv;
      float h = fast_tanh(v);
      hcur[j] = h;
      outf[((base + s) << 8) + j] = h * smask[s];
    }
    __syncthreads();
    xwv = xwn;
  }
}

// ---------------------------------------------------------------------------
// Encoder: 32 steps, 32 rows/wg, 512 threads = 8 waves; each wave owns a
// 32-col slice of ALL THREE weight matrices in 192 VGPRs (bf16 B-frags),
// loaded once. K-loop has zero global loads.
// ---------------------------------------------------------------------------
__launch_bounds__(512, 2)
__global__ void k_enc(const float* __restrict__ gs,
                      const u16* __restrict__ W0b, const u16* __restrict__ W1b,
                      const u16* __restrict__ W2b, const float* __restrict__ wih0,
                      const float* __restrict__ bih0, const float* __restrict__ bhh0,
                      const float* __restrict__ bih1, const float* __restrict__ bhh1,
                      const float* __restrict__ clsW, const float* __restrict__ clsb,
                      float* __restrict__ Ab) {
  __shared__ __align__(16) u16 hA0[32 * 264];
  __shared__ __align__(16) u16 hA1[32 * 264];
  __shared__ float xe[32];
  __shared__ float b0v[256], w0v[256], b1v[256], clsv[256];
  __shared__ float clsbs;
  const int tid = threadIdx.x;
  const int n0 = blockIdx.x * 32;

  for (int c = tid; c < 8192; c += 512) {
    int row = c >> 8, col = c & 255;
    hA0[row * 264 + col] = f2bf(gs[(((size_t)(n0 + row)) << 8) + col]);
    hA1[row * 264 + col] = 0;
  }
  if (tid < 256) {
    b0v[tid] = bih0[tid] + bhh0[tid];
    w0v[tid] = wih0[tid];
    b1v[tid] = bih1[tid] + bhh1[tid];
    clsv[tid] = clsW[tid];
  }
  if (tid < 32) xe[tid] = 1.0f;
  if (tid == 0) clsbs = clsb[0];

  const int l = tid & 63, wv = tid >> 6;
  const int l15 = l & 15, q = l >> 4;
  const int colbase = wv * 32;

  // resident weights: [nt][kt] B-fragments for this wave's 32 columns
  s8v w0[2][8], w1[2][8], w2[2][8];
#pragma unroll
  for (int nt = 0; nt < 2; ++nt) {
    int jj = colbase + nt * 16 + l15;
#pragma unroll
    for (int kt = 0; kt < 8; ++kt) {
      int off = (jj << 8) + kt * 32 + q * 8;
      w0[nt][kt] = load8bf(W0b + off);
      w1[nt][kt] = load8bf(W1b + off);
      w2[nt][kt] = load8bf(W2b + off);
    }
  }
  __syncthreads();

  for (int m = 0; m < 32; ++m) {
    // pass 1: acc = h0 @ Whh0^T  (A from LDS, B from regs)
    f4v acc[2][2];
#pragma unroll
    for (int mt = 0; mt < 2; ++mt)
#pragma unroll
      for (int nt = 0; nt < 2; ++nt) acc[mt][nt] = (f4v){0.f, 0.f, 0.f, 0.f};
#pragma unroll
    for (int kt = 0; kt < 8; ++kt) {
#pragma unroll
      for (int mt = 0; mt < 2; ++mt) {
        s8v a = __builtin_bit_cast(s8v, *(const uint4*)&hA0[(mt * 16 + l15) * 264 + kt * 32 + q * 8]);
        acc[mt][0] = mfma16(a, w0[0][kt], acc[mt][0]);
        acc[mt][1] = mfma16(a, w0[1][kt], acc[mt][1]);
      }
    }
    __syncthreads();
    // epilogue 1: h0 = tanh(acc + xe*w0 + b0)
#pragma unroll
    for (int nt = 0; nt < 2; ++nt) {
      int col = colbase + nt * 16 + l15;
      float wc = w0v[col], bc = b0v[col];
#pragma unroll
      for (int mt = 0; mt < 2; ++mt)
#pragma unroll
        for (int r = 0; r < 4; ++r) {
          int row = mt * 16 + q * 4 + r;
          float v = acc[mt][nt][r] + xe[row] * wc + bc;
          hA0[row * 264 + col] = f2bf(fast_tanh(v));
        }
    }
    __syncthreads();
    // pass 2: acc = h0new @ Wih1^T + h1 @ Whh1^T
#pragma unroll
    for (int mt = 0; mt < 2; ++mt)
#pragma unroll
      for (int nt = 0; nt < 2; ++nt) acc[mt][nt] = (f4v){0.f, 0.f, 0.f, 0.f};
#pragma unroll
    for (int kt = 0; kt < 8; ++kt) {
#pragma unroll
      for (int mt = 0; mt < 2; ++mt) {
        s8v a0 = __builtin_bit_cast(s8v, *(const uint4*)&hA0[(mt * 16 + l15) * 264 + kt * 32 + q * 8]);
        s8v a1 = __builtin_bit_cast(s8v, *(const uint4*)&hA1[(mt * 16 + l15) * 264 + kt * 32 + q * 8]);
        acc[mt][0] = mfma16(a0, w1[0][kt], acc[mt][0]);
        acc[mt][1] = mfma16(a0, w1[1][kt], acc[mt][1]);
        acc[mt][0] = mfma16(a1, w2[0][kt], acc[mt][0]);
        acc[mt][1] = mfma16(a1, w2[1][kt], acc[mt][1]);
      }
    }
    __syncthreads();
    // epilogue 2: h1 = tanh(acc + b1)
#pragma unroll
    for (int nt = 0; nt < 2; ++nt) {
      int col = colbase + nt * 16 + l15;
      float bc = b1v[col];
#pragma unroll
      for (int mt = 0; mt < 2; ++mt)
#pragma unroll
        for (int r = 0; r < 4; ++r) {
          int row = mt * 16 + q * 4 + r;
          float v = acc[mt][nt][r] + bc;
          hA1[row * 264 + col] = f2bf(fast_tanh(v));
        }
    }
    __syncthreads();
    // cls: p = sigmoid(h1 @ clsW^T + clsb); xe <- p; Ab[n*32+m] = p
    if (tid < 256) {
      int row = tid >> 3, seg = tid & 7;
      float sum = 0.f;
#pragma unroll
      for (int u = 0; u < 4; ++u) {
        int col = seg * 32 + u * 8;
#pragma unroll
        for (int e = 0; e < 8; ++e) sum += bf2f(hA1[row * 264 + col + e]) * clsv[col + e];
      }
      sum += __shfl_down(sum, 4, 8);
      sum += __shfl_down(sum, 2, 8);
      sum += __shfl_down(sum, 1, 8);
      if (seg == 0) {
        float pp = fast_sigmoid(sum + clsbs);
        xe[row] = pp;
        Ab[(((size_t)(n0 + row)) << 5) + m] = pp;
      }
    }
    __syncthreads();
  }
}

// ---------------------------------------------------------------------------
// arc_logits[b][j][i] = (j>=max(0,i-32) && j<i) ? Ab[(b*512+i)*32 + j-start] : 0
// ---------------------------------------------------------------------------
__global__ void k_arc(const float* __restrict__ Ab, float* __restrict__ out2) {
  int t = blockIdx.x * 256 + threadIdx.x;  // 4194304 total
  int b = t >> 18;
  int rem = t & 262143;
  int j = rem >> 9, i = rem & 511;
  int start = i - 32;
  if (start < 0) start = 0;
  float v = 0.f;
  if (j >= start && j < i) v = Ab[((((size_t)b << 9) + i) << 5) + (j - start)];
  out2[t] = v;
}

// ---------------------------------------------------------------------------
extern "C" void kernel_launch(void* const* d_in, const int* in_sizes, int n_in,
                              void* d_out, int out_size, void* d_ws, size_t ws_size,
                              hipStream_t stream) {
  const float* input    = (const float*)d_in[0];
  const float* sentinel = (const float*)d_in[1];
  const float* g_Wih0   = (const float*)d_in[2];
  const float* g_Whh0   = (const float*)d_in[3];
  const float* g_bih0   = (const float*)d_in[4];
  const float* g_bhh0   = (const float*)d_in[5];
  const float* g_Wih1   = (const float*)d_in[6];
  const float* g_Whh1   = (const float*)d_in[7];
  const float* g_bih1   = (const float*)d_in[8];
  const float* g_bhh1   = (const float*)d_in[9];
  const float* e_Wih0   = (const float*)d_in[10];
  const float* e_Whh0   = (const float*)d_in[11];
  const float* e_bih0   = (const float*)d_in[12];
  const float* e_bhh0   = (const float*)d_in[13];
  const float* e_Wih1   = (const float*)d_in[14];
  const float* e_Whh1   = (const float*)d_in[15];
  const float* e_bih1   = (const float*)d_in[16];
  const float* e_bhh1   = (const float*)d_in[17];
  const float* cls_W    = (const float*)d_in[18];
  const float* cls_b    = (const float*)d_in[19];
  const float* head_W   = (const float*)d_in[20];
  const float* head_b   = (const float*)d_in[21];
  const float* dep_W    = (const float*)d_in[22];
  const float* dep_b    = (const float*)d_in[23];
  const int* mask       = (const int*)d_in[24];

  float* out = (float*)d_out;
  char* ws = (char*)d_ws;
  float* xw_buf = (float*)ws;                                  // 8 MB
  float* hseq   = (float*)(ws + (8u << 20));                   // 8 MB
  float* gsb    = (float*)(ws + (16u << 20));                  // 8 MB
  float* Ab     = (float*)(ws + (24u << 20));                  // 1 MB
  size_t o = (25u << 20);
  float* Wt0   = (float*)(ws + o); o += 256u << 10;
  float* Wt1   = (float*)(ws + o); o += 256u << 10;
  u16* eb0     = (u16*)(ws + o); o += 128u << 10;
  u16* eb1     = (u16*)(ws + o); o += 128u << 10;
  u16* eb2     = (u16*)(ws + o); o += 128u << 10;
  u16* gw0hi   = (u16*)(ws + o); o += 256u << 10;
  u16* gw0lo   = (u16*)(ws + o); o += 256u << 10;
  u16* gw1hi   = (u16*)(ws + o); o += 128u << 10;
  u16* gw1lo   = (u16*)(ws + o); o += 128u << 10;
  u16* hWhi    = (u16*)(ws + o); o += 64u << 10;
  u16* hWlo    = (u16*)(ws + o); o += 64u << 10;
  u16* dWhi    = (u16*)(ws + o); o += 64u << 10;
  u16* dWlo    = (u16*)(ws + o); o += 64u << 10;

  k_prep<<<2304, 256, 0, stream>>>(g_Whh0, g_Whh1, Wt0, Wt1, e_Whh0, e_Wih1, e_Whh1,
                                   eb0, eb1, eb2, g_Wih0, gw0hi, gw0lo, g_Wih1, gw1hi,
                                   gw1lo, head_W, hWhi, hWlo, dep_W, dWhi, dWlo);
  k_xw0<<<dim3(128, 4), 256, 0, stream>>>(input, sentinel, gw0hi, gw0lo, g_bih0, g_bhh0,
                                          xw_buf);
  k_scan<<<16, 512, 0, stream>>>(xw_buf, Wt0, hseq, nullptr);
  k_gemm<<<dim3(128, 4), 256, 0, stream>>>(hseq, gw1hi, gw1lo, g_bih1, g_bhh1, xw_buf,
                                           256, 256, 0);
  k_scan<<<16, 512, 0, stream>>>(xw_buf, Wt1, gsb, mask);
  k_gemm<<<dim3(128, 2), 256, 0, stream>>>(gsb, hWhi, hWlo, head_b, nullptr, out,
                                           256, 128, 1);
  k_gemm<<<dim3(128, 2), 256, 0, stream>>>(gsb, dWhi, dWlo, dep_b, nullptr, out + 1048576,
                                           256, 128, 1);
  k_enc<<<256, 512, 0, stream>>>(gsb, eb0, eb1, eb2, e_Wih0, e_bih0, e_bhh0,
                                 e_bih1, e_bhh1, cls_W, cls_b, Ab);
  k_arc<<<16384, 256, 0, stream>>>(Ab, out + 2097152);
}

// Round 4
// 1543.335 us; speedup vs baseline: 1.5717x; 1.5717x over previous
//
#include <hip/hip_runtime.h>

typedef unsigned short u16;
typedef short s8v __attribute__((ext_vector_type(8)));
typedef float f4v __attribute__((ext_vector_type(4)));

__device__ __forceinline__ float bf2f(u16 s) {
  unsigned u = ((unsigned)s) << 16;
  return __builtin_bit_cast(float, u);
}
__device__ __forceinline__ u16 f2bf(float f) {
  unsigned u = __builtin_bit_cast(unsigned, f);
  unsigned r = u + 0x7fffu + ((u >> 16) & 1u);  // RNE (no NaN here)
  return (u16)(r >> 16);
}
__device__ __forceinline__ s8v load8bf(const u16* p) {
  return __builtin_bit_cast(s8v, *(const uint4*)p);
}
__device__ __forceinline__ f4v mfma16(s8v a, s8v b, f4v c) {
  return __builtin_amdgcn_mfma_f32_16x16x32_bf16(a, b, c, 0, 0, 0);
}
// 8 consecutive f32 -> bf16 hi + bf16 lo fragments (split precision)
__device__ __forceinline__ void cvt8(const float* p, s8v& hi, s8v& lo) {
  float4 x0 = ((const float4*)p)[0];
  float4 x1 = ((const float4*)p)[1];
  float v[8] = {x0.x, x0.y, x0.z, x0.w, x1.x, x1.y, x1.z, x1.w};
  union { s8v v; u16 a[8]; } H, L;
#pragma unroll
  for (int i = 0; i < 8; ++i) {
    u16 h = f2bf(v[i]);
    H.a[i] = h;
    L.a[i] = f2bf(v[i] - bf2f(h));
  }
  hi = H.v;
  lo = L.v;
}
// tanh(x) = 1 - 2/(1+e^{2x}) via hw exp2/rcp (~1e-6 abs err)
__device__ __forceinline__ float fast_tanh(float x) {
  float t = __builtin_amdgcn_exp2f(x * 2.885390081777927f);
  return 1.f - 2.f * __builtin_amdgcn_rcpf(t + 1.f);
}
__device__ __forceinline__ float fast_sigmoid(float x) {
  float t = __builtin_amdgcn_exp2f(x * -1.4426950408889634f);
  return __builtin_amdgcn_rcpf(1.f + t);
}

// ---------------------------------------------------------------------------
// Prep: transpose g_Whh{0,1} -> f32 [k][j]; e-weights -> bf16; GEMM weights ->
// bf16 hi/lo split pairs.
// ---------------------------------------------------------------------------
__global__ void k_prep(const float* __restrict__ W0, const float* __restrict__ W1,
                       float* __restrict__ Wt0, float* __restrict__ Wt1,
                       const float* __restrict__ E0, const float* __restrict__ E1,
                       const float* __restrict__ E2, u16* __restrict__ B0,
                       u16* __restrict__ B1, u16* __restrict__ B2,
                       const float* __restrict__ gW0, u16* __restrict__ gw0hi,
                       u16* __restrict__ gw0lo, const float* __restrict__ gW1,
                       u16* __restrict__ gw1hi, u16* __restrict__ gw1lo,
                       const float* __restrict__ hW, u16* __restrict__ hWhi,
                       u16* __restrict__ hWlo, const float* __restrict__ dW,
                       u16* __restrict__ dWhi, u16* __restrict__ dWlo) {
  int t = blockIdx.x * 256 + threadIdx.x;  // 589824 total
  if (t < 131072) {
    int layer = t >> 16;
    int idx = t & 65535;
    int k = idx >> 8, j = idx & 255;
    const float* W = layer ? W1 : W0;
    float* Wt = layer ? Wt1 : Wt0;
    Wt[k * 256 + j] = W[j * 256 + k];
  } else if (t < 327680) {
    int c = t - 131072;
    int which = c >> 16;
    int idx = c & 65535;
    const float* src = which == 0 ? E0 : (which == 1 ? E1 : E2);
    u16* dst = which == 0 ? B0 : (which == 1 ? B1 : B2);
    dst[idx] = f2bf(src[idx]);
  } else {
    const float* src;
    u16 *dhi, *dlo;
    int idx;
    if (t < 458752) { idx = t - 327680; src = gW0; dhi = gw0hi; dlo = gw0lo; }
    else if (t < 524288) { idx = t - 458752; src = gW1; dhi = gw1hi; dlo = gw1lo; }
    else if (t < 557056) { idx = t - 524288; src = hW; dhi = hWhi; dlo = hWlo; }
    else { idx = t - 557056; src = dW; dhi = dWhi; dlo = dWlo; }
    float v = src[idx];
    u16 h = f2bf(v);
    dhi[idx] = h;
    dlo[idx] = f2bf(v - bf2f(h));
  }
}

// ---------------------------------------------------------------------------
// xw0 = X @ g_Wih0^T + bih0 + bhh0 (split-bf16, pre-split W). grid (128,4)x256.
// ---------------------------------------------------------------------------
__launch_bounds__(256)
__global__ void k_xw0(const float* __restrict__ input, const float* __restrict__ sentinel,
                      const u16* __restrict__ Whi, const u16* __restrict__ Wlo,
                      const float* __restrict__ b1, const float* __restrict__ b2,
                      float* __restrict__ outxw) {
  const int l = threadIdx.x & 63;
  const int wv = threadIdx.x >> 6;
  const int l15 = l & 15, q = l >> 4;
  const int row0 = blockIdx.x * 64 + wv * 16;
  const int col0 = blockIdx.y * 64;
  int row = row0 + l15;
  int s = row & 511, b = row >> 9;
  const float* aptr = (s == 0) ? sentinel : input + (((size_t)(b * 511 + s - 1)) << 9);
  f4v acc[4];
#pragma unroll
  for (int i = 0; i < 4; ++i) acc[i] = (f4v){0.f, 0.f, 0.f, 0.f};
#pragma unroll
  for (int kt = 0; kt < 16; ++kt) {
    int k0 = kt * 32 + q * 8;
    s8v ah, al;
    cvt8(aptr + k0, ah, al);
#pragma unroll
    for (int nt = 0; nt < 4; ++nt) {
      int j = col0 + nt * 16 + l15;
      s8v wh = load8bf(Whi + ((size_t)j << 9) + k0);
      s8v wl = load8bf(Wlo + ((size_t)j << 9) + k0);
      acc[nt] = mfma16(ah, wh, acc[nt]);
      acc[nt] = mfma16(al, wh, acc[nt]);
      acc[nt] = mfma16(ah, wl, acc[nt]);
    }
  }
#pragma unroll
  for (int nt = 0; nt < 4; ++nt) {
    int col = col0 + nt * 16 + l15;
    float bias = b1[col] + b2[col];
#pragma unroll
    for (int r = 0; r < 4; ++r) {
      int rr = row0 + q * 4 + r;
      outxw[((size_t)rr << 8) + col] = acc[nt][r] + bias;
    }
  }
}

// ---------------------------------------------------------------------------
// Generic split-bf16 C = act(A @ W^T + b1 (+b2)); pre-split W hi/lo.
// act=0: identity; act=1: elu. grid (N/64, J/64) x 256.
// ---------------------------------------------------------------------------
__launch_bounds__(256)
__global__ void k_gemm(const float* __restrict__ A, const u16* __restrict__ Whi,
                       const u16* __restrict__ Wlo, const float* __restrict__ b1,
                       const float* __restrict__ b2, float* __restrict__ outf,
                       int K, int J, int act) {
  const int l = threadIdx.x & 63;
  const int wv = threadIdx.x >> 6;
  const int l15 = l & 15, q = l >> 4;
  const int row0 = blockIdx.x * 64 + wv * 16;
  const int col0 = blockIdx.y * 64;
  const float* aptr = A + (size_t)(row0 + l15) * K;
  f4v acc[4];
#pragma unroll
  for (int i = 0; i < 4; ++i) acc[i] = (f4v){0.f, 0.f, 0.f, 0.f};
  const int nkt = K >> 5;
  for (int kt = 0; kt < nkt; ++kt) {
    int k0 = kt * 32 + q * 8;
    s8v ah, al;
    cvt8(aptr + k0, ah, al);
#pragma unroll
    for (int nt = 0; nt < 4; ++nt) {
      int j = col0 + nt * 16 + l15;
      s8v wh = load8bf(Whi + (size_t)j * K + k0);
      s8v wl = load8bf(Wlo + (size_t)j * K + k0);
      acc[nt] = mfma16(ah, wh, acc[nt]);
      acc[nt] = mfma16(al, wh, acc[nt]);
      acc[nt] = mfma16(ah, wl, acc[nt]);
    }
  }
#pragma unroll
  for (int nt = 0; nt < 4; ++nt) {
    int col = col0 + nt * 16 + l15;
    float bias = b1[col] + (b2 ? b2[col] : 0.f);
#pragma unroll
    for (int r = 0; r < 4; ++r) {
      int rr = row0 + q * 4 + r;
      float v = acc[nt][r] + bias;
      if (act) v = v > 0.f ? v : (__builtin_amdgcn_exp2f(v * 1.4426950408889634f) - 1.f);
      outf[(size_t)rr * J + col] = v;
    }
  }
}

// ---------------------------------------------------------------------------
// Sequential RNN scan, one wg per batch row, pure f32. 1024 threads:
// tid = p*256+j (p in 0..3); thread holds 64 Wt values in VGPRs (w[64] +
// temps ~90 VGPR -> 16 waves x 128 = full per-CU pool, no demotion).
// All lanes of a wave read the SAME hcur float4 -> LDS broadcast, 0 conflicts.
// xw prefetched one step ahead; mask in LDS; fast exp2-based tanh in tail.
// ---------------------------------------------------------------------------
__launch_bounds__(1024)
__global__ void k_scan(const float* __restrict__ xw, const float* __restrict__ Wt,
                       float* __restrict__ outf, const int* __restrict__ mask) {
  __shared__ __align__(16) float hcur[256];
  __shared__ float partials[1024];
  __shared__ float smask[512];
  const int tid = threadIdx.x;
  const int p = tid >> 8, j = tid & 255;
  const int b = blockIdx.x;
  float w[64];
#pragma unroll
  for (int i = 0; i < 64; ++i) w[i] = Wt[(p * 64 + i) * 256 + j];
  if (tid < 256) hcur[tid] = 0.f;
  if (tid < 512) smask[tid] = (tid == 0) ? 1.f : (mask ? (float)mask[b * 511 + tid - 1] : 1.f);
  __syncthreads();
  const float4* hc4 = (const float4*)hcur;
  const size_t base = ((size_t)b << 9);
  float xwv = (tid < 256) ? xw[(base << 8) + j] : 0.f;
  for (int s = 0; s < 512; ++s) {
    float xwn = (tid < 256 && s < 511) ? xw[((base + s + 1) << 8) + j] : 0.f;
    float s0 = 0.f, s1 = 0.f, s2 = 0.f, s3 = 0.f;
#pragma unroll
    for (int i = 0; i < 16; ++i) {
      float4 h4 = hc4[(p << 4) + i];
      s0 = __builtin_fmaf(h4.x, w[4 * i + 0], s0);
      s1 = __builtin_fmaf(h4.y, w[4 * i + 1], s1);
      s2 = __builtin_fmaf(h4.z, w[4 * i + 2], s2);
      s3 = __builtin_fmaf(h4.w, w[4 * i + 3], s3);
    }
    partials[tid] = (s0 + s1) + (s2 + s3);
    __syncthreads();
    if (tid < 256) {
      float v = partials[j] + partials[256 + j] + partials[512 + j] + partials[768 + j] + xwv;
      float h = fast_tanh(v);
      hcur[j] = h;
      outf[((base + s) << 8) + j] = h * smask[s];
    }
    __syncthreads();
    xwv = xwn;
  }
}

// ---------------------------------------------------------------------------
// Encoder: 32 steps, 32 rows/wg, 512 threads = 8 waves; each wave owns a
// 32-col slice of ALL THREE weight matrices in 192 VGPRs (bf16 B-frags),
// loaded once. K-loop has zero global loads.
// ---------------------------------------------------------------------------
__launch_bounds__(512, 2)
__global__ void k_enc(const float* __restrict__ gs,
                      const u16* __restrict__ W0b, const u16* __restrict__ W1b,
                      const u16* __restrict__ W2b, const float* __restrict__ wih0,
                      const float* __restrict__ bih0, const float* __restrict__ bhh0,
                      const float* __restrict__ bih1, const float* __restrict__ bhh1,
                      const float* __restrict__ clsW, const float* __restrict__ clsb,
                      float* __restrict__ Ab) {
  __shared__ __align__(16) u16 hA0[32 * 264];
  __shared__ __align__(16) u16 hA1[32 * 264];
  __shared__ float xe[32];
  __shared__ float b0v[256], w0v[256], b1v[256], clsv[256];
  __shared__ float clsbs;
  const int tid = threadIdx.x;
  const int n0 = blockIdx.x * 32;

  for (int c = tid; c < 8192; c += 512) {
    int row = c >> 8, col = c & 255;
    hA0[row * 264 + col] = f2bf(gs[(((size_t)(n0 + row)) << 8) + col]);
    hA1[row * 264 + col] = 0;
  }
  if (tid < 256) {
    b0v[tid] = bih0[tid] + bhh0[tid];
    w0v[tid] = wih0[tid];
    b1v[tid] = bih1[tid] + bhh1[tid];
    clsv[tid] = clsW[tid];
  }
  if (tid < 32) xe[tid] = 1.0f;
  if (tid == 0) clsbs = clsb[0];

  const int l = tid & 63, wv = tid >> 6;
  const int l15 = l & 15, q = l >> 4;
  const int colbase = wv * 32;

  // resident weights: [nt][kt] B-fragments for this wave's 32 columns
  s8v w0[2][8], w1[2][8], w2[2][8];
#pragma unroll
  for (int nt = 0; nt < 2; ++nt) {
    int jj = colbase + nt * 16 + l15;
#pragma unroll
    for (int kt = 0; kt < 8; ++kt) {
      int off = (jj << 8) + kt * 32 + q * 8;
      w0[nt][kt] = load8bf(W0b + off);
      w1[nt][kt] = load8bf(W1b + off);
      w2[nt][kt] = load8bf(W2b + off);
    }
  }
  __syncthreads();

  for (int m = 0; m < 32; ++m) {
    // pass 1: acc = h0 @ Whh0^T  (A from LDS, B from regs)
    f4v acc[2][2];
#pragma unroll
    for (int mt = 0; mt < 2; ++mt)
#pragma unroll
      for (int nt = 0; nt < 2; ++nt) acc[mt][nt] = (f4v){0.f, 0.f, 0.f, 0.f};
#pragma unroll
    for (int kt = 0; kt < 8; ++kt) {
#pragma unroll
      for (int mt = 0; mt < 2; ++mt) {
        s8v a = __builtin_bit_cast(s8v, *(const uint4*)&hA0[(mt * 16 + l15) * 264 + kt * 32 + q * 8]);
        acc[mt][0] = mfma16(a, w0[0][kt], acc[mt][0]);
        acc[mt][1] = mfma16(a, w0[1][kt], acc[mt][1]);
      }
    }
    __syncthreads();
    // epilogue 1: h0 = tanh(acc + xe*w0 + b0)
#pragma unroll
    for (int nt = 0; nt < 2; ++nt) {
      int col = colbase + nt * 16 + l15;
      float wc = w0v[col], bc = b0v[col];
#pragma unroll
      for (int mt = 0; mt < 2; ++mt)
#pragma unroll
        for (int r = 0; r < 4; ++r) {
          int row = mt * 16 + q * 4 + r;
          float v = acc[mt][nt][r] + xe[row] * wc + bc;
          hA0[row * 264 + col] = f2bf(fast_tanh(v));
        }
    }
    __syncthreads();
    // pass 2: acc = h0new @ Wih1^T + h1 @ Whh1^T
#pragma unroll
    for (int mt = 0; mt < 2; ++mt)
#pragma unroll
      for (int nt = 0; nt < 2; ++nt) acc[mt][nt] = (f4v){0.f, 0.f, 0.f, 0.f};
#pragma unroll
    for (int kt = 0; kt < 8; ++kt) {
#pragma unroll
      for (int mt = 0; mt < 2; ++mt) {
        s8v a0 = __builtin_bit_cast(s8v, *(const uint4*)&hA0[(mt * 16 + l15) * 264 + kt * 32 + q * 8]);
        s8v a1 = __builtin_bit_cast(s8v, *(const uint4*)&hA1[(mt * 16 + l15) * 264 + kt * 32 + q * 8]);
        acc[mt][0] = mfma16(a0, w1[0][kt], acc[mt][0]);
        acc[mt][1] = mfma16(a0, w1[1][kt], acc[mt][1]);
        acc[mt][0] = mfma16(a1, w2[0][kt], acc[mt][0]);
        acc[mt][1] = mfma16(a1, w2[1][kt], acc[mt][1]);
      }
    }
    __syncthreads();
    // epilogue 2: h1 = tanh(acc + b1)
#pragma unroll
    for (int nt = 0; nt < 2; ++nt) {
      int col = colbase + nt * 16 + l15;
      float bc = b1v[col];
#pragma unroll
      for (int mt = 0; mt < 2; ++mt)
#pragma unroll
        for (int r = 0; r < 4; ++r) {
          int row = mt * 16 + q * 4 + r;
          float v = acc[mt][nt][r] + bc;
          hA1[row * 264 + col] = f2bf(fast_tanh(v));
        }
    }
    __syncthreads();
    // cls: p = sigmoid(h1 @ clsW^T + clsb); xe <- p; Ab[n*32+m] = p
    if (tid < 256) {
      int row = tid >> 3, seg = tid & 7;
      float sum = 0.f;
#pragma unroll
      for (int u = 0; u < 4; ++u) {
        int col = seg * 32 + u * 8;
#pragma unroll
        for (int e = 0; e < 8; ++e) sum += bf2f(hA1[row * 264 + col + e]) * clsv[col + e];
      }
      sum += __shfl_down(sum, 4, 8);
      sum += __shfl_down(sum, 2, 8);
      sum += __shfl_down(sum, 1, 8);
      if (seg == 0) {
        float pp = fast_sigmoid(sum + clsbs);
        xe[row] = pp;
        Ab[(((size_t)(n0 + row)) << 5) + m] = pp;
      }
    }
    __syncthreads();
  }
}

// ---------------------------------------------------------------------------
// arc_logits[b][j][i] = (j>=max(0,i-32) && j<i) ? Ab[(b*512+i)*32 + j-start] : 0
// ---------------------------------------------------------------------------
__global__ void k_arc(const float* __restrict__ Ab, float* __restrict__ out2) {
  int t = blockIdx.x * 256 + threadIdx.x;  // 4194304 total
  int b = t >> 18;
  int rem = t & 262143;
  int j = rem >> 9, i = rem & 511;
  int start = i - 32;
  if (start < 0) start = 0;
  float v = 0.f;
  if (j >= start && j < i) v = Ab[((((size_t)b << 9) + i) << 5) + (j - start)];
  out2[t] = v;
}

// ---------------------------------------------------------------------------
extern "C" void kernel_launch(void* const* d_in, const int* in_sizes, int n_in,
                              void* d_out, int out_size, void* d_ws, size_t ws_size,
                              hipStream_t stream) {
  const float* input    = (const float*)d_in[0];
  const float* sentinel = (const float*)d_in[1];
  const float* g_Wih0   = (const float*)d_in[2];
  const float* g_Whh0   = (const float*)d_in[3];
  const float* g_bih0   = (const float*)d_in[4];
  const float* g_bhh0   = (const float*)d_in[5];
  const float* g_Wih1   = (const float*)d_in[6];
  const float* g_Whh1   = (const float*)d_in[7];
  const float* g_bih1   = (const float*)d_in[8];
  const float* g_bhh1   = (const float*)d_in[9];
  const float* e_Wih0   = (const float*)d_in[10];
  const float* e_Whh0   = (const float*)d_in[11];
  const float* e_bih0   = (const float*)d_in[12];
  const float* e_bhh0   = (const float*)d_in[13];
  const float* e_Wih1   = (const float*)d_in[14];
  const float* e_Whh1   = (const float*)d_in[15];
  const float* e_bih1   = (const float*)d_in[16];
  const float* e_bhh1   = (const float*)d_in[17];
  const float* cls_W    = (const float*)d_in[18];
  const float* cls_b    = (const float*)d_in[19];
  const float* head_W   = (const float*)d_in[20];
  const float* head_b   = (const float*)d_in[21];
  const float* dep_W    = (const float*)d_in[22];
  const float* dep_b    = (const float*)d_in[23];
  const int* mask       = (const int*)d_in[24];

  float* out = (float*)d_out;
  char* ws = (char*)d_ws;
  float* xw_buf = (float*)ws;                                  // 8 MB
  float* hseq   = (float*)(ws + (8u << 20));                   // 8 MB
  float* gsb    = (float*)(ws + (16u << 20));                  // 8 MB
  float* Ab     = (float*)(ws + (24u << 20));                  // 1 MB
  size_t o = (25u << 20);
  float* Wt0   = (float*)(ws + o); o += 256u << 10;
  float* Wt1   = (float*)(ws + o); o += 256u << 10;
  u16* eb0     = (u16*)(ws + o); o += 128u << 10;
  u16* eb1     = (u16*)(ws + o); o += 128u << 10;
  u16* eb2     = (u16*)(ws + o); o += 128u << 10;
  u16* gw0hi   = (u16*)(ws + o); o += 256u << 10;
  u16* gw0lo   = (u16*)(ws + o); o += 256u << 10;
  u16* gw1hi   = (u16*)(ws + o); o += 128u << 10;
  u16* gw1lo   = (u16*)(ws + o); o += 128u << 10;
  u16* hWhi    = (u16*)(ws + o); o += 64u << 10;
  u16* hWlo    = (u16*)(ws + o); o += 64u << 10;
  u16* dWhi    = (u16*)(ws + o); o += 64u << 10;
  u16* dWlo    = (u16*)(ws + o); o += 64u << 10;

  k_prep<<<2304, 256, 0, stream>>>(g_Whh0, g_Whh1, Wt0, Wt1, e_Whh0, e_Wih1, e_Whh1,
                                   eb0, eb1, eb2, g_Wih0, gw0hi, gw0lo, g_Wih1, gw1hi,
                                   gw1lo, head_W, hWhi, hWlo, dep_W, dWhi, dWlo);
  k_xw0<<<dim3(128, 4), 256, 0, stream>>>(input, sentinel, gw0hi, gw0lo, g_bih0, g_bhh0,
                                          xw_buf);
  k_scan<<<16, 1024, 0, stream>>>(xw_buf, Wt0, hseq, nullptr);
  k_gemm<<<dim3(128, 4), 256, 0, stream>>>(hseq, gw1hi, gw1lo, g_bih1, g_bhh1, xw_buf,
                                           256, 256, 0);
  k_scan<<<16, 1024, 0, stream>>>(xw_buf, Wt1, gsb, mask);
  k_gemm<<<dim3(128, 2), 256, 0, stream>>>(gsb, hWhi, hWlo, head_b, nullptr, out,
                                           256, 128, 1);
  k_gemm<<<dim3(128, 2), 256, 0, stream>>>(gsb, dWhi, dWlo, dep_b, nullptr, out + 1048576,
                                           256, 128, 1);
  k_enc<<<256, 512, 0, stream>>>(gsb, eb0, eb1, eb2, e_Wih0, e_bih0, e_bhh0,
                                 e_bih1, e_bhh1, cls_W, cls_b, Ab);
  k_arc<<<16384, 256, 0, stream>>>(Ab, out + 2097152);
}

// Round 5
// 1384.333 us; speedup vs baseline: 1.7522x; 1.1149x over previous
//
#include <hip/hip_runtime.h>

typedef unsigned short u16;
typedef short s8v __attribute__((ext_vector_type(8)));
typedef float f4v __attribute__((ext_vector_type(4)));

__device__ __forceinline__ float bf2f(u16 s) {
  unsigned u = ((unsigned)s) << 16;
  return __builtin_bit_cast(float, u);
}
__device__ __forceinline__ u16 f2bf(float f) {
  unsigned u = __builtin_bit_cast(unsigned, f);
  unsigned r = u + 0x7fffu + ((u >> 16) & 1u);  // RNE (no NaN here)
  return (u16)(r >> 16);
}
__device__ __forceinline__ s8v load8bf(const u16* p) {
  return __builtin_bit_cast(s8v, *(const uint4*)p);
}
__device__ __forceinline__ f4v mfma16(s8v a, s8v b, f4v c) {
  return __builtin_amdgcn_mfma_f32_16x16x32_bf16(a, b, c, 0, 0, 0);
}
// 8 consecutive f32 -> bf16 hi + bf16 lo fragments (split precision)
__device__ __forceinline__ void cvt8(const float* p, s8v& hi, s8v& lo) {
  float4 x0 = ((const float4*)p)[0];
  float4 x1 = ((const float4*)p)[1];
  float v[8] = {x0.x, x0.y, x0.z, x0.w, x1.x, x1.y, x1.z, x1.w};
  union { s8v v; u16 a[8]; } H, L;
#pragma unroll
  for (int i = 0; i < 8; ++i) {
    u16 h = f2bf(v[i]);
    H.a[i] = h;
    L.a[i] = f2bf(v[i] - bf2f(h));
  }
  hi = H.v;
  lo = L.v;
}
// tanh(x) = 1 - 2/(1+e^{2x}) via hw exp2/rcp (~1e-6 abs err)
__device__ __forceinline__ float fast_tanh(float x) {
  float t = __builtin_amdgcn_exp2f(x * 2.885390081777927f);
  return 1.f - 2.f * __builtin_amdgcn_rcpf(t + 1.f);
}
__device__ __forceinline__ float fast_sigmoid(float x) {
  float t = __builtin_amdgcn_exp2f(x * -1.4426950408889634f);
  return __builtin_amdgcn_rcpf(1.f + t);
}

// ---------------------------------------------------------------------------
// Prep: g_Whh{0,1} -> bf16 row-major; e-weights -> bf16; GEMM weights ->
// bf16 hi/lo split pairs; mask -> f32 table [s][b].
// ---------------------------------------------------------------------------
__global__ void k_prep(const float* __restrict__ W0, const float* __restrict__ W1,
                       u16* __restrict__ whh0b, u16* __restrict__ whh1b,
                       const float* __restrict__ E0, const float* __restrict__ E1,
                       const float* __restrict__ E2, u16* __restrict__ B0,
                       u16* __restrict__ B1, u16* __restrict__ B2,
                       const float* __restrict__ gW0, u16* __restrict__ gw0hi,
                       u16* __restrict__ gw0lo, const float* __restrict__ gW1,
                       u16* __restrict__ gw1hi, u16* __restrict__ gw1lo,
                       const float* __restrict__ hW, u16* __restrict__ hWhi,
                       u16* __restrict__ hWlo, const float* __restrict__ dW,
                       u16* __restrict__ dWhi, u16* __restrict__ dWlo,
                       const int* __restrict__ mask, float* __restrict__ maskfb) {
  int t = blockIdx.x * 256 + threadIdx.x;  // 598016 total
  if (t < 131072) {
    int layer = t >> 16;
    int idx = t & 65535;
    const float* W = layer ? W1 : W0;
    u16* dst = layer ? whh1b : whh0b;
    dst[idx] = f2bf(W[idx]);
  } else if (t < 327680) {
    int c = t - 131072;
    int which = c >> 16;
    int idx = c & 65535;
    const float* src = which == 0 ? E0 : (which == 1 ? E1 : E2);
    u16* dst = which == 0 ? B0 : (which == 1 ? B1 : B2);
    dst[idx] = f2bf(src[idx]);
  } else if (t < 589824) {
    const float* src;
    u16 *dhi, *dlo;
    int idx;
    if (t < 458752) { idx = t - 327680; src = gW0; dhi = gw0hi; dlo = gw0lo; }
    else if (t < 524288) { idx = t - 458752; src = gW1; dhi = gw1hi; dlo = gw1lo; }
    else if (t < 557056) { idx = t - 524288; src = hW; dhi = hWhi; dlo = hWlo; }
    else { idx = t - 557056; src = dW; dhi = dWhi; dlo = dWlo; }
    float v = src[idx];
    u16 h = f2bf(v);
    dhi[idx] = h;
    dlo[idx] = f2bf(v - bf2f(h));
  } else if (t < 598016) {
    int c = t - 589824;  // c = s*16 + b
    int s = c >> 4, b = c & 15;
    maskfb[c] = (s == 0) ? 1.f : (float)mask[b * 511 + s - 1];
  }
}

// ---------------------------------------------------------------------------
// xw0 = X @ g_Wih0^T + bih0 + bhh0 (split-bf16, pre-split W). grid (128,4)x256.
// ---------------------------------------------------------------------------
__launch_bounds__(256)
__global__ void k_xw0(const float* __restrict__ input, const float* __restrict__ sentinel,
                      const u16* __restrict__ Whi, const u16* __restrict__ Wlo,
                      const float* __restrict__ b1, const float* __restrict__ b2,
                      float* __restrict__ outxw) {
  const int l = threadIdx.x & 63;
  const int wv = threadIdx.x >> 6;
  const int l15 = l & 15, q = l >> 4;
  const int row0 = blockIdx.x * 64 + wv * 16;
  const int col0 = blockIdx.y * 64;
  int row = row0 + l15;
  int s = row & 511, b = row >> 9;
  const float* aptr = (s == 0) ? sentinel : input + (((size_t)(b * 511 + s - 1)) << 9);
  f4v acc[4];
#pragma unroll
  for (int i = 0; i < 4; ++i) acc[i] = (f4v){0.f, 0.f, 0.f, 0.f};
#pragma unroll
  for (int kt = 0; kt < 16; ++kt) {
    int k0 = kt * 32 + q * 8;
    s8v ah, al;
    cvt8(aptr + k0, ah, al);
#pragma unroll
    for (int nt = 0; nt < 4; ++nt) {
      int j = col0 + nt * 16 + l15;
      s8v wh = load8bf(Whi + ((size_t)j << 9) + k0);
      s8v wl = load8bf(Wlo + ((size_t)j << 9) + k0);
      acc[nt] = mfma16(ah, wh, acc[nt]);
      acc[nt] = mfma16(al, wh, acc[nt]);
      acc[nt] = mfma16(ah, wl, acc[nt]);
    }
  }
#pragma unroll
  for (int nt = 0; nt < 4; ++nt) {
    int col = col0 + nt * 16 + l15;
    float bias = b1[col] + b2[col];
#pragma unroll
    for (int r = 0; r < 4; ++r) {
      int rr = row0 + q * 4 + r;
      outxw[((size_t)rr << 8) + col] = acc[nt][r] + bias;
    }
  }
}

// ---------------------------------------------------------------------------
// Generic split-bf16 C = act(A @ W^T + b1 (+b2)); pre-split W hi/lo.
// act=0: identity; act=1: elu. grid (N/64, J/64) x 256.
// ---------------------------------------------------------------------------
__launch_bounds__(256)
__global__ void k_gemm(const float* __restrict__ A, const u16* __restrict__ Whi,
                       const u16* __restrict__ Wlo, const float* __restrict__ b1,
                       const float* __restrict__ b2, float* __restrict__ outf,
                       int K, int J, int act) {
  const int l = threadIdx.x & 63;
  const int wv = threadIdx.x >> 6;
  const int l15 = l & 15, q = l >> 4;
  const int row0 = blockIdx.x * 64 + wv * 16;
  const int col0 = blockIdx.y * 64;
  const float* aptr = A + (size_t)(row0 + l15) * K;
  f4v acc[4];
#pragma unroll
  for (int i = 0; i < 4; ++i) acc[i] = (f4v){0.f, 0.f, 0.f, 0.f};
  const int nkt = K >> 5;
  for (int kt = 0; kt < nkt; ++kt) {
    int k0 = kt * 32 + q * 8;
    s8v ah, al;
    cvt8(aptr + k0, ah, al);
#pragma unroll
    for (int nt = 0; nt < 4; ++nt) {
      int j = col0 + nt * 16 + l15;
      s8v wh = load8bf(Whi + (size_t)j * K + k0);
      s8v wl = load8bf(Wlo + (size_t)j * K + k0);
      acc[nt] = mfma16(ah, wh, acc[nt]);
      acc[nt] = mfma16(al, wh, acc[nt]);
      acc[nt] = mfma16(ah, wl, acc[nt]);
    }
  }
#pragma unroll
  for (int nt = 0; nt < 4; ++nt) {
    int col = col0 + nt * 16 + l15;
    float bias = b1[col] + (b2 ? b2[col] : 0.f);
#pragma unroll
    for (int r = 0; r < 4; ++r) {
      int rr = row0 + q * 4 + r;
      float v = acc[nt][r] + bias;
      if (act) v = v > 0.f ? v : (__builtin_amdgcn_exp2f(v * 1.4426950408889634f) - 1.f);
      outf[(size_t)rr * J + col] = v;
    }
  }
}

// ---------------------------------------------------------------------------
// MFMA RNN scan: ONE workgroup, 512 threads = 8 waves, all 16 batch rows
// together. Per step: D[j][b] = sum_k Whh[j][k] * H[b][k] via 16x16x32 MFMA,
// A = Whh rows (bf16, stationary in VGPRs, 32 cols/wave), B = H (bf16,
// double-buffered in LDS, dense b128 frags). Epilogue: v = D + xw (f32,
// prefetched), h = tanh(v); H'[b][k] = bf16(h); out = f32 h * mask.
// Single barrier per step (write image != read image).
// ---------------------------------------------------------------------------
#define HPITCH 264
#define HIMG (16 * HPITCH)
__launch_bounds__(512, 2)
__global__ void k_scan_m(const float* __restrict__ xw, const u16* __restrict__ Wb,
                         float* __restrict__ outf, const float* __restrict__ maskf) {
  __shared__ u16 H[2 * HIMG];
  __shared__ float mtab[8192];
  const int tid = threadIdx.x;
  const int l = tid & 63, wv = tid >> 6;
  const int l15 = l & 15, q = l >> 4;
  const int b = l15;  // batch row this lane's C-fragment belongs to

  // stationary A fragments: wave wv owns output cols [wv*32, wv*32+32)
  s8v a[2][8];
#pragma unroll
  for (int mt = 0; mt < 2; ++mt) {
    int j = wv * 32 + mt * 16 + l15;
#pragma unroll
    for (int kt = 0; kt < 8; ++kt)
      a[mt][kt] = load8bf(Wb + (j << 8) + kt * 32 + q * 8);
  }
  // zero image 0 (h0 = 0)
  for (int c = tid; c < HIMG; c += 512) H[c] = 0;
  // mask table [s][b]
  if (maskf)
    for (int c = tid; c < 8192; c += 512) mtab[c] = maskf[c];
  __syncthreads();

  const int kb0 = wv * 32 + q * 4;        // k-base of this thread's mt=0 values
  const size_t xrow = ((size_t)(b << 9)); // n = b*512 + s
  float4 xn0 = *(const float4*)&xw[(xrow << 8) + kb0];
  float4 xn1 = *(const float4*)&xw[(xrow << 8) + kb0 + 16];

  for (int s = 0; s < 512; ++s) {
    float4 xc0 = xn0, xc1 = xn1;
    int sp = (s < 511) ? s + 1 : 511;
    xn0 = *(const float4*)&xw[((xrow + sp) << 8) + kb0];
    xn1 = *(const float4*)&xw[((xrow + sp) << 8) + kb0 + 16];

    const int par = s & 1;
    const u16* Hr = H + par * HIMG + l15 * HPITCH;
    f4v acc0 = (f4v){0.f, 0.f, 0.f, 0.f};
    f4v acc1 = (f4v){0.f, 0.f, 0.f, 0.f};
#pragma unroll
    for (int kt = 0; kt < 8; ++kt) {
      s8v bb = load8bf(Hr + kt * 32 + q * 8);
      acc0 = mfma16(a[0][kt], bb, acc0);
      acc1 = mfma16(a[1][kt], bb, acc1);
    }

    float mf = maskf ? mtab[(s << 4) + b] : 1.f;
    u16* Hw = H + (1 - par) * HIMG + b * HPITCH;
    float* orow = outf + (((xrow + s) << 8));
    // mt = 0
    {
      float h0 = fast_tanh(acc0[0] + xc0.x);
      float h1 = fast_tanh(acc0[1] + xc0.y);
      float h2 = fast_tanh(acc0[2] + xc0.z);
      float h3 = fast_tanh(acc0[3] + xc0.w);
      union { uint2 u; u16 a[4]; } pk;
      pk.a[0] = f2bf(h0); pk.a[1] = f2bf(h1); pk.a[2] = f2bf(h2); pk.a[3] = f2bf(h3);
      *(uint2*)&Hw[kb0] = pk.u;
      *(float4*)&orow[kb0] = (float4){h0 * mf, h1 * mf, h2 * mf, h3 * mf};
    }
    // mt = 1
    {
      float h0 = fast_tanh(acc1[0] + xc1.x);
      float h1 = fast_tanh(acc1[1] + xc1.y);
      float h2 = fast_tanh(acc1[2] + xc1.z);
      float h3 = fast_tanh(acc1[3] + xc1.w);
      union { uint2 u; u16 a[4]; } pk;
      pk.a[0] = f2bf(h0); pk.a[1] = f2bf(h1); pk.a[2] = f2bf(h2); pk.a[3] = f2bf(h3);
      *(uint2*)&Hw[kb0 + 16] = pk.u;
      *(float4*)&orow[kb0 + 16] = (float4){h0 * mf, h1 * mf, h2 * mf, h3 * mf};
    }
    __syncthreads();
  }
}

// ---------------------------------------------------------------------------
// Encoder: 32 steps, 32 rows/wg, 512 threads = 8 waves; weights resident in
// VGPRs (loaded once); h0/h1 bf16 in LDS.
// ---------------------------------------------------------------------------
__launch_bounds__(512, 2)
__global__ void k_enc(const float* __restrict__ gs,
                      const u16* __restrict__ W0b, const u16* __restrict__ W1b,
                      const u16* __restrict__ W2b, const float* __restrict__ wih0,
                      const float* __restrict__ bih0, const float* __restrict__ bhh0,
                      const float* __restrict__ bih1, const float* __restrict__ bhh1,
                      const float* __restrict__ clsW, const float* __restrict__ clsb,
                      float* __restrict__ Ab) {
  __shared__ __align__(16) u16 hA0[32 * 264];
  __shared__ __align__(16) u16 hA1[32 * 264];
  __shared__ float xe[32];
  __shared__ float b0v[256], w0v[256], b1v[256], clsv[256];
  __shared__ float clsbs;
  const int tid = threadIdx.x;
  const int n0 = blockIdx.x * 32;

  for (int c = tid; c < 8192; c += 512) {
    int row = c >> 8, col = c & 255;
    hA0[row * 264 + col] = f2bf(gs[(((size_t)(n0 + row)) << 8) + col]);
    hA1[row * 264 + col] = 0;
  }
  if (tid < 256) {
    b0v[tid] = bih0[tid] + bhh0[tid];
    w0v[tid] = wih0[tid];
    b1v[tid] = bih1[tid] + bhh1[tid];
    clsv[tid] = clsW[tid];
  }
  if (tid < 32) xe[tid] = 1.0f;
  if (tid == 0) clsbs = clsb[0];

  const int l = tid & 63, wv = tid >> 6;
  const int l15 = l & 15, q = l >> 4;
  const int colbase = wv * 32;

  s8v w0[2][8], w1[2][8], w2[2][8];
#pragma unroll
  for (int nt = 0; nt < 2; ++nt) {
    int jj = colbase + nt * 16 + l15;
#pragma unroll
    for (int kt = 0; kt < 8; ++kt) {
      int off = (jj << 8) + kt * 32 + q * 8;
      w0[nt][kt] = load8bf(W0b + off);
      w1[nt][kt] = load8bf(W1b + off);
      w2[nt][kt] = load8bf(W2b + off);
    }
  }
  __syncthreads();

  for (int m = 0; m < 32; ++m) {
    f4v acc[2][2];
#pragma unroll
    for (int mt = 0; mt < 2; ++mt)
#pragma unroll
      for (int nt = 0; nt < 2; ++nt) acc[mt][nt] = (f4v){0.f, 0.f, 0.f, 0.f};
#pragma unroll
    for (int kt = 0; kt < 8; ++kt) {
#pragma unroll
      for (int mt = 0; mt < 2; ++mt) {
        s8v a = __builtin_bit_cast(s8v, *(const uint4*)&hA0[(mt * 16 + l15) * 264 + kt * 32 + q * 8]);
        acc[mt][0] = mfma16(a, w0[0][kt], acc[mt][0]);
        acc[mt][1] = mfma16(a, w0[1][kt], acc[mt][1]);
      }
    }
    __syncthreads();
#pragma unroll
    for (int nt = 0; nt < 2; ++nt) {
      int col = colbase + nt * 16 + l15;
      float wc = w0v[col], bc = b0v[col];
#pragma unroll
      for (int mt = 0; mt < 2; ++mt)
#pragma unroll
        for (int r = 0; r < 4; ++r) {
          int row = mt * 16 + q * 4 + r;
          float v = acc[mt][nt][r] + xe[row] * wc + bc;
          hA0[row * 264 + col] = f2bf(fast_tanh(v));
        }
    }
    __syncthreads();
#pragma unroll
    for (int mt = 0; mt < 2; ++mt)
#pragma unroll
      for (int nt = 0; nt < 2; ++nt) acc[mt][nt] = (f4v){0.f, 0.f, 0.f, 0.f};
#pragma unroll
    for (int kt = 0; kt < 8; ++kt) {
#pragma unroll
      for (int mt = 0; mt < 2; ++mt) {
        s8v a0 = __builtin_bit_cast(s8v, *(const uint4*)&hA0[(mt * 16 + l15) * 264 + kt * 32 + q * 8]);
        s8v a1 = __builtin_bit_cast(s8v, *(const uint4*)&hA1[(mt * 16 + l15) * 264 + kt * 32 + q * 8]);
        acc[mt][0] = mfma16(a0, w1[0][kt], acc[mt][0]);
        acc[mt][1] = mfma16(a0, w1[1][kt], acc[mt][1]);
        acc[mt][0] = mfma16(a1, w2[0][kt], acc[mt][0]);
        acc[mt][1] = mfma16(a1, w2[1][kt], acc[mt][1]);
      }
    }
    __syncthreads();
#pragma unroll
    for (int nt = 0; nt < 2; ++nt) {
      int col = colbase + nt * 16 + l15;
      float bc = b1v[col];
#pragma unroll
      for (int mt = 0; mt < 2; ++mt)
#pragma unroll
        for (int r = 0; r < 4; ++r) {
          int row = mt * 16 + q * 4 + r;
          float v = acc[mt][nt][r] + bc;
          hA1[row * 264 + col] = f2bf(fast_tanh(v));
        }
    }
    __syncthreads();
    if (tid < 256) {
      int row = tid >> 3, seg = tid & 7;
      float sum = 0.f;
#pragma unroll
      for (int u = 0; u < 4; ++u) {
        int col = seg * 32 + u * 8;
#pragma unroll
        for (int e = 0; e < 8; ++e) sum += bf2f(hA1[row * 264 + col + e]) * clsv[col + e];
      }
      sum += __shfl_down(sum, 4, 8);
      sum += __shfl_down(sum, 2, 8);
      sum += __shfl_down(sum, 1, 8);
      if (seg == 0) {
        float pp = fast_sigmoid(sum + clsbs);
        xe[row] = pp;
        Ab[(((size_t)(n0 + row)) << 5) + m] = pp;
      }
    }
    __syncthreads();
  }
}

// ---------------------------------------------------------------------------
// arc_logits[b][j][i] = (j>=max(0,i-32) && j<i) ? Ab[(b*512+i)*32 + j-start] : 0
// ---------------------------------------------------------------------------
__global__ void k_arc(const float* __restrict__ Ab, float* __restrict__ out2) {
  int t = blockIdx.x * 256 + threadIdx.x;  // 4194304 total
  int b = t >> 18;
  int rem = t & 262143;
  int j = rem >> 9, i = rem & 511;
  int start = i - 32;
  if (start < 0) start = 0;
  float v = 0.f;
  if (j >= start && j < i) v = Ab[((((size_t)b << 9) + i) << 5) + (j - start)];
  out2[t] = v;
}

// ---------------------------------------------------------------------------
extern "C" void kernel_launch(void* const* d_in, const int* in_sizes, int n_in,
                              void* d_out, int out_size, void* d_ws, size_t ws_size,
                              hipStream_t stream) {
  const float* input    = (const float*)d_in[0];
  const float* sentinel = (const float*)d_in[1];
  const float* g_Wih0   = (const float*)d_in[2];
  const float* g_Whh0   = (const float*)d_in[3];
  const float* g_bih0   = (const float*)d_in[4];
  const float* g_bhh0   = (const float*)d_in[5];
  const float* g_Wih1   = (const float*)d_in[6];
  const float* g_Whh1   = (const float*)d_in[7];
  const float* g_bih1   = (const float*)d_in[8];
  const float* g_bhh1   = (const float*)d_in[9];
  const float* e_Wih0   = (const float*)d_in[10];
  const float* e_Whh0   = (const float*)d_in[11];
  const float* e_bih0   = (const float*)d_in[12];
  const float* e_bhh0   = (const float*)d_in[13];
  const float* e_Wih1   = (const float*)d_in[14];
  const float* e_Whh1   = (const float*)d_in[15];
  const float* e_bih1   = (const float*)d_in[16];
  const float* e_bhh1   = (const float*)d_in[17];
  const float* cls_W    = (const float*)d_in[18];
  const float* cls_b    = (const float*)d_in[19];
  const float* head_W   = (const float*)d_in[20];
  const float* head_b   = (const float*)d_in[21];
  const float* dep_W    = (const float*)d_in[22];
  const float* dep_b    = (const float*)d_in[23];
  const int* mask       = (const int*)d_in[24];

  float* out = (float*)d_out;
  char* ws = (char*)d_ws;
  float* xw_buf = (float*)ws;                                  // 8 MB
  float* hseq   = (float*)(ws + (8u << 20));                   // 8 MB
  float* gsb    = (float*)(ws + (16u << 20));                  // 8 MB
  float* Ab     = (float*)(ws + (24u << 20));                  // 1 MB
  size_t o = (25u << 20);
  u16* whh0b   = (u16*)(ws + o); o += 128u << 10;
  u16* whh1b   = (u16*)(ws + o); o += 128u << 10;
  float* maskfb= (float*)(ws + o); o += 32u << 10;
  u16* eb0     = (u16*)(ws + o); o += 128u << 10;
  u16* eb1     = (u16*)(ws + o); o += 128u << 10;
  u16* eb2     = (u16*)(ws + o); o += 128u << 10;
  u16* gw0hi   = (u16*)(ws + o); o += 256u << 10;
  u16* gw0lo   = (u16*)(ws + o); o += 256u << 10;
  u16* gw1hi   = (u16*)(ws + o); o += 128u << 10;
  u16* gw1lo   = (u16*)(ws + o); o += 128u << 10;
  u16* hWhi    = (u16*)(ws + o); o += 64u << 10;
  u16* hWlo    = (u16*)(ws + o); o += 64u << 10;
  u16* dWhi    = (u16*)(ws + o); o += 64u << 10;
  u16* dWlo    = (u16*)(ws + o); o += 64u << 10;

  k_prep<<<2336, 256, 0, stream>>>(g_Whh0, g_Whh1, whh0b, whh1b, e_Whh0, e_Wih1, e_Whh1,
                                   eb0, eb1, eb2, g_Wih0, gw0hi, gw0lo, g_Wih1, gw1hi,
                                   gw1lo, head_W, hWhi, hWlo, dep_W, dWhi, dWlo,
                                   mask, maskfb);
  k_xw0<<<dim3(128, 4), 256, 0, stream>>>(input, sentinel, gw0hi, gw0lo, g_bih0, g_bhh0,
                                          xw_buf);
  k_scan_m<<<1, 512, 0, stream>>>(xw_buf, whh0b, hseq, nullptr);
  k_gemm<<<dim3(128, 4), 256, 0, stream>>>(hseq, gw1hi, gw1lo, g_bih1, g_bhh1, xw_buf,
                                           256, 256, 0);
  k_scan_m<<<1, 512, 0, stream>>>(xw_buf, whh1b, gsb, maskfb);
  k_gemm<<<dim3(128, 2), 256, 0, stream>>>(gsb, hWhi, hWlo, head_b, nullptr, out,
                                           256, 128, 1);
  k_gemm<<<dim3(128, 2), 256, 0, stream>>>(gsb, dWhi, dWlo, dep_b, nullptr, out + 1048576,
                                           256, 128, 1);
  k_enc<<<256, 512, 0, stream>>>(gsb, eb0, eb1, eb2, e_Wih0, e_bih0, e_bhh0,
                                 e_bih1, e_bhh1, cls_W, cls_b, Ab);
  k_arc<<<16384, 256, 0, stream>>>(Ab, out + 2097152);
}

// Round 6
// 1327.764 us; speedup vs baseline: 1.8269x; 1.0426x over previous
//
#include <hip/hip_runtime.h>

typedef unsigned short u16;
typedef short s8v __attribute__((ext_vector_type(8)));
typedef float f4v __attribute__((ext_vector_type(4)));

__device__ __forceinline__ float bf2f(u16 s) {
  unsigned u = ((unsigned)s) << 16;
  return __builtin_bit_cast(float, u);
}
__device__ __forceinline__ u16 f2bf(float f) {
  unsigned u = __builtin_bit_cast(unsigned, f);
  unsigned r = u + 0x7fffu + ((u >> 16) & 1u);  // RNE (no NaN here)
  return (u16)(r >> 16);
}
__device__ __forceinline__ s8v load8bf(const u16* p) {
  return __builtin_bit_cast(s8v, *(const uint4*)p);
}
__device__ __forceinline__ f4v mfma16(s8v a, s8v b, f4v c) {
  return __builtin_amdgcn_mfma_f32_16x16x32_bf16(a, b, c, 0, 0, 0);
}
// Pin a 128-bit fragment into VGPRs: asm outputs cannot be rematerialized or
// sunk into the loop, defeating the backend's demote-to-scratch heuristic.
__device__ __forceinline__ s8v pin8(s8v x) {
  union { s8v v; unsigned u[4]; } t;
  t.v = x;
  asm volatile("" : "+v"(t.u[0]), "+v"(t.u[1]), "+v"(t.u[2]), "+v"(t.u[3]));
  return t.v;
}
// LDS-only barrier: __syncthreads() drains vmcnt(0) (global stores/prefetch);
// the scan only needs LDS ordering across the double-buffered H images.
__device__ __forceinline__ void barrier_lds() {
  asm volatile("s_waitcnt lgkmcnt(0)\n\ts_barrier" ::: "memory");
}
// 8 consecutive f32 -> bf16 hi + bf16 lo fragments (split precision)
__device__ __forceinline__ void cvt8(const float* p, s8v& hi, s8v& lo) {
  float4 x0 = ((const float4*)p)[0];
  float4 x1 = ((const float4*)p)[1];
  float v[8] = {x0.x, x0.y, x0.z, x0.w, x1.x, x1.y, x1.z, x1.w};
  union { s8v v; u16 a[8]; } H, L;
#pragma unroll
  for (int i = 0; i < 8; ++i) {
    u16 h = f2bf(v[i]);
    H.a[i] = h;
    L.a[i] = f2bf(v[i] - bf2f(h));
  }
  hi = H.v;
  lo = L.v;
}
// tanh(x) = 1 - 2/(1+e^{2x}) via hw exp2/rcp (~1e-6 abs err)
__device__ __forceinline__ float fast_tanh(float x) {
  float t = __builtin_amdgcn_exp2f(x * 2.885390081777927f);
  return 1.f - 2.f * __builtin_amdgcn_rcpf(t + 1.f);
}
__device__ __forceinline__ float fast_sigmoid(float x) {
  float t = __builtin_amdgcn_exp2f(x * -1.4426950408889634f);
  return __builtin_amdgcn_rcpf(1.f + t);
}

// ---------------------------------------------------------------------------
// Prep: g_Whh{0,1} -> bf16 row-major; e-weights -> bf16; GEMM weights ->
// bf16 hi/lo split pairs; mask -> f32 table [s][b].
// ---------------------------------------------------------------------------
__global__ void k_prep(const float* __restrict__ W0, const float* __restrict__ W1,
                       u16* __restrict__ whh0b, u16* __restrict__ whh1b,
                       const float* __restrict__ E0, const float* __restrict__ E1,
                       const float* __restrict__ E2, u16* __restrict__ B0,
                       u16* __restrict__ B1, u16* __restrict__ B2,
                       const float* __restrict__ gW0, u16* __restrict__ gw0hi,
                       u16* __restrict__ gw0lo, const float* __restrict__ gW1,
                       u16* __restrict__ gw1hi, u16* __restrict__ gw1lo,
                       const float* __restrict__ hW, u16* __restrict__ hWhi,
                       u16* __restrict__ hWlo, const float* __restrict__ dW,
                       u16* __restrict__ dWhi, u16* __restrict__ dWlo,
                       const int* __restrict__ mask, float* __restrict__ maskfb) {
  int t = blockIdx.x * 256 + threadIdx.x;  // 598016 total
  if (t < 131072) {
    int layer = t >> 16;
    int idx = t & 65535;
    const float* W = layer ? W1 : W0;
    u16* dst = layer ? whh1b : whh0b;
    dst[idx] = f2bf(W[idx]);
  } else if (t < 327680) {
    int c = t - 131072;
    int which = c >> 16;
    int idx = c & 65535;
    const float* src = which == 0 ? E0 : (which == 1 ? E1 : E2);
    u16* dst = which == 0 ? B0 : (which == 1 ? B1 : B2);
    dst[idx] = f2bf(src[idx]);
  } else if (t < 589824) {
    const float* src;
    u16 *dhi, *dlo;
    int idx;
    if (t < 458752) { idx = t - 327680; src = gW0; dhi = gw0hi; dlo = gw0lo; }
    else if (t < 524288) { idx = t - 458752; src = gW1; dhi = gw1hi; dlo = gw1lo; }
    else if (t < 557056) { idx = t - 524288; src = hW; dhi = hWhi; dlo = hWlo; }
    else { idx = t - 557056; src = dW; dhi = dWhi; dlo = dWlo; }
    float v = src[idx];
    u16 h = f2bf(v);
    dhi[idx] = h;
    dlo[idx] = f2bf(v - bf2f(h));
  } else if (t < 598016) {
    int c = t - 589824;  // c = s*16 + b
    int s = c >> 4, b = c & 15;
    maskfb[c] = (s == 0) ? 1.f : (float)mask[b * 511 + s - 1];
  }
}

// ---------------------------------------------------------------------------
// xw0 = X @ g_Wih0^T + bih0 + bhh0 (split-bf16, pre-split W). grid (128,4)x256.
// ---------------------------------------------------------------------------
__launch_bounds__(256)
__global__ void k_xw0(const float* __restrict__ input, const float* __restrict__ sentinel,
                      const u16* __restrict__ Whi, const u16* __restrict__ Wlo,
                      const float* __restrict__ b1, const float* __restrict__ b2,
                      float* __restrict__ outxw) {
  const int l = threadIdx.x & 63;
  const int wv = threadIdx.x >> 6;
  const int l15 = l & 15, q = l >> 4;
  const int row0 = blockIdx.x * 64 + wv * 16;
  const int col0 = blockIdx.y * 64;
  int row = row0 + l15;
  int s = row & 511, b = row >> 9;
  const float* aptr = (s == 0) ? sentinel : input + (((size_t)(b * 511 + s - 1)) << 9);
  f4v acc[4];
#pragma unroll
  for (int i = 0; i < 4; ++i) acc[i] = (f4v){0.f, 0.f, 0.f, 0.f};
#pragma unroll
  for (int kt = 0; kt < 16; ++kt) {
    int k0 = kt * 32 + q * 8;
    s8v ah, al;
    cvt8(aptr + k0, ah, al);
#pragma unroll
    for (int nt = 0; nt < 4; ++nt) {
      int j = col0 + nt * 16 + l15;
      s8v wh = load8bf(Whi + ((size_t)j << 9) + k0);
      s8v wl = load8bf(Wlo + ((size_t)j << 9) + k0);
      acc[nt] = mfma16(ah, wh, acc[nt]);
      acc[nt] = mfma16(al, wh, acc[nt]);
      acc[nt] = mfma16(ah, wl, acc[nt]);
    }
  }
#pragma unroll
  for (int nt = 0; nt < 4; ++nt) {
    int col = col0 + nt * 16 + l15;
    float bias = b1[col] + b2[col];
#pragma unroll
    for (int r = 0; r < 4; ++r) {
      int rr = row0 + q * 4 + r;
      outxw[((size_t)rr << 8) + col] = acc[nt][r] + bias;
    }
  }
}

// ---------------------------------------------------------------------------
// Generic split-bf16 C = act(A @ W^T + b1 (+b2)); pre-split W hi/lo.
// act=0: identity; act=1: elu. grid (N/64, J/64) x 256.
// ---------------------------------------------------------------------------
__launch_bounds__(256)
__global__ void k_gemm(const float* __restrict__ A, const u16* __restrict__ Whi,
                       const u16* __restrict__ Wlo, const float* __restrict__ b1,
                       const float* __restrict__ b2, float* __restrict__ outf,
                       int K, int J, int act) {
  const int l = threadIdx.x & 63;
  const int wv = threadIdx.x >> 6;
  const int l15 = l & 15, q = l >> 4;
  const int row0 = blockIdx.x * 64 + wv * 16;
  const int col0 = blockIdx.y * 64;
  const float* aptr = A + (size_t)(row0 + l15) * K;
  f4v acc[4];
#pragma unroll
  for (int i = 0; i < 4; ++i) acc[i] = (f4v){0.f, 0.f, 0.f, 0.f};
  const int nkt = K >> 5;
  for (int kt = 0; kt < nkt; ++kt) {
    int k0 = kt * 32 + q * 8;
    s8v ah, al;
    cvt8(aptr + k0, ah, al);
#pragma unroll
    for (int nt = 0; nt < 4; ++nt) {
      int j = col0 + nt * 16 + l15;
      s8v wh = load8bf(Whi + (size_t)j * K + k0);
      s8v wl = load8bf(Wlo + (size_t)j * K + k0);
      acc[nt] = mfma16(ah, wh, acc[nt]);
      acc[nt] = mfma16(al, wh, acc[nt]);
      acc[nt] = mfma16(ah, wl, acc[nt]);
    }
  }
#pragma unroll
  for (int nt = 0; nt < 4; ++nt) {
    int col = col0 + nt * 16 + l15;
    float bias = b1[col] + (b2 ? b2[col] : 0.f);
#pragma unroll
    for (int r = 0; r < 4; ++r) {
      int rr = row0 + q * 4 + r;
      float v = acc[nt][r] + bias;
      if (act) v = v > 0.f ? v : (__builtin_amdgcn_exp2f(v * 1.4426950408889634f) - 1.f);
      outf[(size_t)rr * J + col] = v;
    }
  }
}

// ---------------------------------------------------------------------------
// MFMA RNN scan: ONE workgroup, 256 threads = 4 waves (1/SIMD). Wave wv owns
// output cols [wv*64, wv*64+64) as 4 m-tiles; Whh A-frags PINNED in VGPRs
// (a[4][8] = 128 regs). B = H (bf16, double-buffered LDS). Per step: 8
// ds_read_b128 + 32 MFMA + tanh epilogue + ds_write, one LDS-only barrier.
// xw prefetched 2 steps ahead (loads stay in flight across raw barriers).
// ---------------------------------------------------------------------------
#define HPITCH 264
#define HIMG (16 * HPITCH)
__launch_bounds__(256, 1)
__global__ void k_scan_m(const float* __restrict__ xw, const u16* __restrict__ Wb,
                         float* __restrict__ outf, const float* __restrict__ maskf) {
  __shared__ u16 H[2 * HIMG];
  __shared__ float mtab[8192];
  const int tid = threadIdx.x;
  const int l = tid & 63, wv = tid >> 6;  // wv 0..3
  const int l15 = l & 15, q = l >> 4;
  const int b = l15;  // batch row of this lane's C-fragment column

  // stationary A fragments (Whh rows), pinned into VGPRs
  s8v a[4][8];
#pragma unroll
  for (int mt = 0; mt < 4; ++mt) {
    int j = wv * 64 + mt * 16 + l15;
#pragma unroll
    for (int kt = 0; kt < 8; ++kt)
      a[mt][kt] = pin8(load8bf(Wb + (j << 8) + kt * 32 + q * 8));
  }
  for (int c = tid; c < HIMG; c += 256) H[c] = 0;  // h0 = 0 (image 0)
  for (int c = tid; c < 8192; c += 256) mtab[c] = maskf ? maskf[c] : 1.f;
  __syncthreads();

  const int kb = wv * 64 + q * 4;            // + mt*16 -> this thread's j-quad
  const float* xbase = xw + ((size_t)b << 17);  // row n = b*512+s, elem j

  float4 xA[4], xB[4];
#pragma unroll
  for (int mt = 0; mt < 4; ++mt) {
    xA[mt] = *(const float4*)&xbase[kb + mt * 16];
    xB[mt] = *(const float4*)&xbase[256 + kb + mt * 16];
  }

  auto STEP = [&](int s, int par, float4* xc) {
    const u16* Hr = H + par * HIMG + l15 * HPITCH;
    f4v acc[4];
#pragma unroll
    for (int mt = 0; mt < 4; ++mt) acc[mt] = (f4v){0.f, 0.f, 0.f, 0.f};
#pragma unroll
    for (int kt = 0; kt < 8; ++kt) {
      s8v bb = load8bf(Hr + kt * 32 + q * 8);
#pragma unroll
      for (int mt = 0; mt < 4; ++mt) acc[mt] = mfma16(a[mt][kt], bb, acc[mt]);
    }
    float mf = mtab[(s << 4) + b];
    u16* Hw = H + (1 - par) * HIMG + b * HPITCH;
    float* orow = outf + ((size_t)b << 17) + ((size_t)s << 8);
#pragma unroll
    for (int mt = 0; mt < 4; ++mt) {
      float h0 = fast_tanh(acc[mt][0] + xc[mt].x);
      float h1 = fast_tanh(acc[mt][1] + xc[mt].y);
      float h2 = fast_tanh(acc[mt][2] + xc[mt].z);
      float h3 = fast_tanh(acc[mt][3] + xc[mt].w);
      union { uint2 u; u16 a4[4]; } pk;
      pk.a4[0] = f2bf(h0); pk.a4[1] = f2bf(h1); pk.a4[2] = f2bf(h2); pk.a4[3] = f2bf(h3);
      *(uint2*)&Hw[kb + mt * 16] = pk.u;
      *(float4*)&orow[kb + mt * 16] = (float4){h0 * mf, h1 * mf, h2 * mf, h3 * mf};
    }
  };

  for (int s = 0; s < 512; s += 2) {
    STEP(s, 0, xA);
    int sp = s + 2; if (sp > 511) sp = 511;
#pragma unroll
    for (int mt = 0; mt < 4; ++mt)
      xA[mt] = *(const float4*)&xbase[(sp << 8) + kb + mt * 16];
    barrier_lds();
    STEP(s + 1, 1, xB);
    int sq = s + 3; if (sq > 511) sq = 511;
#pragma unroll
    for (int mt = 0; mt < 4; ++mt)
      xB[mt] = *(const float4*)&xbase[(sq << 8) + kb + mt * 16];
    barrier_lds();
  }
}

// ---------------------------------------------------------------------------
// Encoder: 32 steps, 32 rows/wg, 512 threads = 8 waves; weights resident
// (compiler may re-stream from L2; 16 waves/CU hide it); h0/h1 bf16 in LDS.
// ---------------------------------------------------------------------------
__launch_bounds__(512, 2)
__global__ void k_enc(const float* __restrict__ gs,
                      const u16* __restrict__ W0b, const u16* __restrict__ W1b,
                      const u16* __restrict__ W2b, const float* __restrict__ wih0,
                      const float* __restrict__ bih0, const float* __restrict__ bhh0,
                      const float* __restrict__ bih1, const float* __restrict__ bhh1,
                      const float* __restrict__ clsW, const float* __restrict__ clsb,
                      float* __restrict__ Ab) {
  __shared__ __align__(16) u16 hA0[32 * 264];
  __shared__ __align__(16) u16 hA1[32 * 264];
  __shared__ float xe[32];
  __shared__ float b0v[256], w0v[256], b1v[256], clsv[256];
  __shared__ float clsbs;
  const int tid = threadIdx.x;
  const int n0 = blockIdx.x * 32;

  for (int c = tid; c < 8192; c += 512) {
    int row = c >> 8, col = c & 255;
    hA0[row * 264 + col] = f2bf(gs[(((size_t)(n0 + row)) << 8) + col]);
    hA1[row * 264 + col] = 0;
  }
  if (tid < 256) {
    b0v[tid] = bih0[tid] + bhh0[tid];
    w0v[tid] = wih0[tid];
    b1v[tid] = bih1[tid] + bhh1[tid];
    clsv[tid] = clsW[tid];
  }
  if (tid < 32) xe[tid] = 1.0f;
  if (tid == 0) clsbs = clsb[0];

  const int l = tid & 63, wv = tid >> 6;
  const int l15 = l & 15, q = l >> 4;
  const int colbase = wv * 32;

  s8v w0[2][8], w1[2][8], w2[2][8];
#pragma unroll
  for (int nt = 0; nt < 2; ++nt) {
    int jj = colbase + nt * 16 + l15;
#pragma unroll
    for (int kt = 0; kt < 8; ++kt) {
      int off = (jj << 8) + kt * 32 + q * 8;
      w0[nt][kt] = load8bf(W0b + off);
      w1[nt][kt] = load8bf(W1b + off);
      w2[nt][kt] = load8bf(W2b + off);
    }
  }
  __syncthreads();

  for (int m = 0; m < 32; ++m) {
    f4v acc[2][2];
#pragma unroll
    for (int mt = 0; mt < 2; ++mt)
#pragma unroll
      for (int nt = 0; nt < 2; ++nt) acc[mt][nt] = (f4v){0.f, 0.f, 0.f, 0.f};
#pragma unroll
    for (int kt = 0; kt < 8; ++kt) {
#pragma unroll
      for (int mt = 0; mt < 2; ++mt) {
        s8v a = __builtin_bit_cast(s8v, *(const uint4*)&hA0[(mt * 16 + l15) * 264 + kt * 32 + q * 8]);
        acc[mt][0] = mfma16(a, w0[0][kt], acc[mt][0]);
        acc[mt][1] = mfma16(a, w0[1][kt], acc[mt][1]);
      }
    }
    __syncthreads();
#pragma unroll
    for (int nt = 0; nt < 2; ++nt) {
      int col = colbase + nt * 16 + l15;
      float wc = w0v[col], bc = b0v[col];
#pragma unroll
      for (int mt = 0; mt < 2; ++mt)
#pragma unroll
        for (int r = 0; r < 4; ++r) {
          int row = mt * 16 + q * 4 + r;
          float v = acc[mt][nt][r] + xe[row] * wc + bc;
          hA0[row * 264 + col] = f2bf(fast_tanh(v));
        }
    }
    __syncthreads();
#pragma unroll
    for (int mt = 0; mt < 2; ++mt)
#pragma unroll
      for (int nt = 0; nt < 2; ++nt) acc[mt][nt] = (f4v){0.f, 0.f, 0.f, 0.f};
#pragma unroll
    for (int kt = 0; kt < 8; ++kt) {
#pragma unroll
      for (int mt = 0; mt < 2; ++mt) {
        s8v a0 = __builtin_bit_cast(s8v, *(const uint4*)&hA0[(mt * 16 + l15) * 264 + kt * 32 + q * 8]);
        s8v a1 = __builtin_bit_cast(s8v, *(const uint4*)&hA1[(mt * 16 + l15) * 264 + kt * 32 + q * 8]);
        acc[mt][0] = mfma16(a0, w1[0][kt], acc[mt][0]);
        acc[mt][1] = mfma16(a0, w1[1][kt], acc[mt][1]);
        acc[mt][0] = mfma16(a1, w2[0][kt], acc[mt][0]);
        acc[mt][1] = mfma16(a1, w2[1][kt], acc[mt][1]);
      }
    }
    __syncthreads();
#pragma unroll
    for (int nt = 0; nt < 2; ++nt) {
      int col = colbase + nt * 16 + l15;
      float bc = b1v[col];
#pragma unroll
      for (int mt = 0; mt < 2; ++mt)
#pragma unroll
        for (int r = 0; r < 4; ++r) {
          int row = mt * 16 + q * 4 + r;
          float v = acc[mt][nt][r] + bc;
          hA1[row * 264 + col] = f2bf(fast_tanh(v));
        }
    }
    __syncthreads();
    if (tid < 256) {
      int row = tid >> 3, seg = tid & 7;
      float sum = 0.f;
#pragma unroll
      for (int u = 0; u < 4; ++u) {
        int col = seg * 32 + u * 8;
#pragma unroll
        for (int e = 0; e < 8; ++e) sum += bf2f(hA1[row * 264 + col + e]) * clsv[col + e];
      }
      sum += __shfl_down(sum, 4, 8);
      sum += __shfl_down(sum, 2, 8);
      sum += __shfl_down(sum, 1, 8);
      if (seg == 0) {
        float pp = fast_sigmoid(sum + clsbs);
        xe[row] = pp;
        Ab[(((size_t)(n0 + row)) << 5) + m] = pp;
      }
    }
    __syncthreads();
  }
}

// ---------------------------------------------------------------------------
// arc_logits[b][j][i] = (j>=max(0,i-32) && j<i) ? Ab[(b*512+i)*32 + j-start] : 0
// ---------------------------------------------------------------------------
__global__ void k_arc(const float* __restrict__ Ab, float* __restrict__ out2) {
  int t = blockIdx.x * 256 + threadIdx.x;  // 4194304 total
  int b = t >> 18;
  int rem = t & 262143;
  int j = rem >> 9, i = rem & 511;
  int start = i - 32;
  if (start < 0) start = 0;
  float v = 0.f;
  if (j >= start && j < i) v = Ab[((((size_t)b << 9) + i) << 5) + (j - start)];
  out2[t] = v;
}

// ---------------------------------------------------------------------------
extern "C" void kernel_launch(void* const* d_in, const int* in_sizes, int n_in,
                              void* d_out, int out_size, void* d_ws, size_t ws_size,
                              hipStream_t stream) {
  const float* input    = (const float*)d_in[0];
  const float* sentinel = (const float*)d_in[1];
  const float* g_Wih0   = (const float*)d_in[2];
  const float* g_Whh0   = (const float*)d_in[3];
  const float* g_bih0   = (const float*)d_in[4];
  const float* g_bhh0   = (const float*)d_in[5];
  const float* g_Wih1   = (const float*)d_in[6];
  const float* g_Whh1   = (const float*)d_in[7];
  const float* g_bih1   = (const float*)d_in[8];
  const float* g_bhh1   = (const float*)d_in[9];
  const float* e_Wih0   = (const float*)d_in[10];
  const float* e_Whh0   = (const float*)d_in[11];
  const float* e_bih0   = (const float*)d_in[12];
  const float* e_bhh0   = (const float*)d_in[13];
  const float* e_Wih1   = (const float*)d_in[14];
  const float* e_Whh1   = (const float*)d_in[15];
  const float* e_bih1   = (const float*)d_in[16];
  const float* e_bhh1   = (const float*)d_in[17];
  const float* cls_W    = (const float*)d_in[18];
  const float* cls_b    = (const float*)d_in[19];
  const float* head_W   = (const float*)d_in[20];
  const float* head_b   = (const float*)d_in[21];
  const float* dep_W    = (const float*)d_in[22];
  const float* dep_b    = (const float*)d_in[23];
  const int* mask       = (const int*)d_in[24];

  float* out = (float*)d_out;
  char* ws = (char*)d_ws;
  float* xw_buf = (float*)ws;                                  // 8 MB
  float* hseq   = (float*)(ws + (8u << 20));                   // 8 MB
  float* gsb    = (float*)(ws + (16u << 20));                  // 8 MB
  float* Ab     = (float*)(ws + (24u << 20));                  // 1 MB
  size_t o = (25u << 20);
  u16* whh0b   = (u16*)(ws + o); o += 128u << 10;
  u16* whh1b   = (u16*)(ws + o); o += 128u << 10;
  float* maskfb= (float*)(ws + o); o += 32u << 10;
  u16* eb0     = (u16*)(ws + o); o += 128u << 10;
  u16* eb1     = (u16*)(ws + o); o += 128u << 10;
  u16* eb2     = (u16*)(ws + o); o += 128u << 10;
  u16* gw0hi   = (u16*)(ws + o); o += 256u << 10;
  u16* gw0lo   = (u16*)(ws + o); o += 256u << 10;
  u16* gw1hi   = (u16*)(ws + o); o += 128u << 10;
  u16* gw1lo   = (u16*)(ws + o); o += 128u << 10;
  u16* hWhi    = (u16*)(ws + o); o += 64u << 10;
  u16* hWlo    = (u16*)(ws + o); o += 64u << 10;
  u16* dWhi    = (u16*)(ws + o); o += 64u << 10;
  u16* dWlo    = (u16*)(ws + o); o += 64u << 10;

  k_prep<<<2336, 256, 0, stream>>>(g_Whh0, g_Whh1, whh0b, whh1b, e_Whh0, e_Wih1, e_Whh1,
                                   eb0, eb1, eb2, g_Wih0, gw0hi, gw0lo, g_Wih1, gw1hi,
                                   gw1lo, head_W, hWhi, hWlo, dep_W, dWhi, dWlo,
                                   mask, maskfb);
  k_xw0<<<dim3(128, 4), 256, 0, stream>>>(input, sentinel, gw0hi, gw0lo, g_bih0, g_bhh0,
                                          xw_buf);
  k_scan_m<<<1, 256, 0, stream>>>(xw_buf, whh0b, hseq, nullptr);
  k_gemm<<<dim3(128, 4), 256, 0, stream>>>(hseq, gw1hi, gw1lo, g_bih1, g_bhh1, xw_buf,
                                           256, 256, 0);
  k_scan_m<<<1, 256, 0, stream>>>(xw_buf, whh1b, gsb, maskfb);
  k_gemm<<<dim3(128, 2), 256, 0, stream>>>(gsb, hWhi, hWlo, head_b, nullptr, out,
                                           256, 128, 1);
  k_gemm<<<dim3(128, 2), 256, 0, stream>>>(gsb, dWhi, dWlo, dep_b, nullptr, out + 1048576,
                                           256, 128, 1);
  k_enc<<<256, 512, 0, stream>>>(gsb, eb0, eb1, eb2, e_Wih0, e_bih0, e_bhh0,
                                 e_bih1, e_bhh1, cls_W, cls_b, Ab);
  k_arc<<<16384, 256, 0, stream>>>(Ab, out + 2097152);
}

// Round 7
// 961.805 us; speedup vs baseline: 2.5220x; 1.3805x over previous
//
#include <hip/hip_runtime.h>

typedef unsigned short u16;
typedef short s8v __attribute__((ext_vector_type(8)));
typedef float f4v __attribute__((ext_vector_type(4)));

__device__ __forceinline__ float bf2f(u16 s) {
  unsigned u = ((unsigned)s) << 16;
  return __builtin_bit_cast(float, u);
}
__device__ __forceinline__ u16 f2bf(float f) {
  unsigned u = __builtin_bit_cast(unsigned, f);
  unsigned r = u + 0x7fffu + ((u >> 16) & 1u);  // RNE (no NaN here)
  return (u16)(r >> 16);
}
__device__ __forceinline__ s8v load8bf(const u16* p) {
  return __builtin_bit_cast(s8v, *(const uint4*)p);
}
__device__ __forceinline__ f4v mfma16(s8v a, s8v b, f4v c) {
  return __builtin_amdgcn_mfma_f32_16x16x32_bf16(a, b, c, 0, 0, 0);
}
// Pin a 128-bit fragment into registers: asm outputs cannot be rematerialized
// or sunk into the loop, defeating the backend's demote-to-scratch heuristic.
__device__ __forceinline__ s8v pin8(s8v x) {
  union { s8v v; unsigned u[4]; } t;
  t.v = x;
  asm volatile("" : "+v"(t.u[0]), "+v"(t.u[1]), "+v"(t.u[2]), "+v"(t.u[3]));
  return t.v;
}
// LDS-only barrier: __syncthreads() drains vmcnt(0) (global stores/prefetch);
// the scan only needs LDS ordering across the double-buffered H images.
__device__ __forceinline__ void barrier_lds() {
  asm volatile("s_waitcnt lgkmcnt(0)\n\ts_barrier" ::: "memory");
}
// 8 consecutive f32 -> bf16 hi + bf16 lo fragments (split precision)
__device__ __forceinline__ void cvt8(const float* p, s8v& hi, s8v& lo) {
  float4 x0 = ((const float4*)p)[0];
  float4 x1 = ((const float4*)p)[1];
  float v[8] = {x0.x, x0.y, x0.z, x0.w, x1.x, x1.y, x1.z, x1.w};
  union { s8v v; u16 a[8]; } H, L;
#pragma unroll
  for (int i = 0; i < 8; ++i) {
    u16 h = f2bf(v[i]);
    H.a[i] = h;
    L.a[i] = f2bf(v[i] - bf2f(h));
  }
  hi = H.v;
  lo = L.v;
}
// tanh(x) = 1 - 2/(1+e^{2x}) via hw exp2/rcp (~1e-6 abs err)
__device__ __forceinline__ float fast_tanh(float x) {
  float t = __builtin_amdgcn_exp2f(x * 2.885390081777927f);
  return 1.f - 2.f * __builtin_amdgcn_rcpf(t + 1.f);
}
__device__ __forceinline__ float fast_sigmoid(float x) {
  float t = __builtin_amdgcn_exp2f(x * -1.4426950408889634f);
  return __builtin_amdgcn_rcpf(1.f + t);
}

// ---------------------------------------------------------------------------
// Prep: g_Whh{0,1} -> bf16 row-major; e-weights -> bf16; GEMM weights ->
// bf16 hi/lo split pairs; mask -> f32 table [s][b].
// ---------------------------------------------------------------------------
__global__ void k_prep(const float* __restrict__ W0, const float* __restrict__ W1,
                       u16* __restrict__ whh0b, u16* __restrict__ whh1b,
                       const float* __restrict__ E0, const float* __restrict__ E1,
                       const float* __restrict__ E2, u16* __restrict__ B0,
                       u16* __restrict__ B1, u16* __restrict__ B2,
                       const float* __restrict__ gW0, u16* __restrict__ gw0hi,
                       u16* __restrict__ gw0lo, const float* __restrict__ gW1,
                       u16* __restrict__ gw1hi, u16* __restrict__ gw1lo,
                       const float* __restrict__ hW, u16* __restrict__ hWhi,
                       u16* __restrict__ hWlo, const float* __restrict__ dW,
                       u16* __restrict__ dWhi, u16* __restrict__ dWlo,
                       const int* __restrict__ mask, float* __restrict__ maskfb) {
  int t = blockIdx.x * 256 + threadIdx.x;  // 598016 total
  if (t < 131072) {
    int layer = t >> 16;
    int idx = t & 65535;
    const float* W = layer ? W1 : W0;
    u16* dst = layer ? whh1b : whh0b;
    dst[idx] = f2bf(W[idx]);
  } else if (t < 327680) {
    int c = t - 131072;
    int which = c >> 16;
    int idx = c & 65535;
    const float* src = which == 0 ? E0 : (which == 1 ? E1 : E2);
    u16* dst = which == 0 ? B0 : (which == 1 ? B1 : B2);
    dst[idx] = f2bf(src[idx]);
  } else if (t < 589824) {
    const float* src;
    u16 *dhi, *dlo;
    int idx;
    if (t < 458752) { idx = t - 327680; src = gW0; dhi = gw0hi; dlo = gw0lo; }
    else if (t < 524288) { idx = t - 458752; src = gW1; dhi = gw1hi; dlo = gw1lo; }
    else if (t < 557056) { idx = t - 524288; src = hW; dhi = hWhi; dlo = hWlo; }
    else { idx = t - 557056; src = dW; dhi = dWhi; dlo = dWlo; }
    float v = src[idx];
    u16 h = f2bf(v);
    dhi[idx] = h;
    dlo[idx] = f2bf(v - bf2f(h));
  } else if (t < 598016) {
    int c = t - 589824;  // c = s*16 + b
    int s = c >> 4, b = c & 15;
    maskfb[c] = (s == 0) ? 1.f : (float)mask[b * 511 + s - 1];
  }
}

// ---------------------------------------------------------------------------
// xw0 = X @ g_Wih0^T + bih0 + bhh0 (split-bf16, pre-split W). grid (128,4)x256.
// ---------------------------------------------------------------------------
__launch_bounds__(256)
__global__ void k_xw0(const float* __restrict__ input, const float* __restrict__ sentinel,
                      const u16* __restrict__ Whi, const u16* __restrict__ Wlo,
                      const float* __restrict__ b1, const float* __restrict__ b2,
                      float* __restrict__ outxw) {
  const int l = threadIdx.x & 63;
  const int wv = threadIdx.x >> 6;
  const int l15 = l & 15, q = l >> 4;
  const int row0 = blockIdx.x * 64 + wv * 16;
  const int col0 = blockIdx.y * 64;
  int row = row0 + l15;
  int s = row & 511, b = row >> 9;
  const float* aptr = (s == 0) ? sentinel : input + (((size_t)(b * 511 + s - 1)) << 9);
  f4v acc[4];
#pragma unroll
  for (int i = 0; i < 4; ++i) acc[i] = (f4v){0.f, 0.f, 0.f, 0.f};
#pragma unroll
  for (int kt = 0; kt < 16; ++kt) {
    int k0 = kt * 32 + q * 8;
    s8v ah, al;
    cvt8(aptr + k0, ah, al);
#pragma unroll
    for (int nt = 0; nt < 4; ++nt) {
      int j = col0 + nt * 16 + l15;
      s8v wh = load8bf(Whi + ((size_t)j << 9) + k0);
      s8v wl = load8bf(Wlo + ((size_t)j << 9) + k0);
      acc[nt] = mfma16(ah, wh, acc[nt]);
      acc[nt] = mfma16(al, wh, acc[nt]);
      acc[nt] = mfma16(ah, wl, acc[nt]);
    }
  }
#pragma unroll
  for (int nt = 0; nt < 4; ++nt) {
    int col = col0 + nt * 16 + l15;
    float bias = b1[col] + b2[col];
#pragma unroll
    for (int r = 0; r < 4; ++r) {
      int rr = row0 + q * 4 + r;
      outxw[((size_t)rr << 8) + col] = acc[nt][r] + bias;
    }
  }
}

// ---------------------------------------------------------------------------
// Generic split-bf16 C = act(A @ W^T + b1 (+b2)); pre-split W hi/lo.
// act=0: identity; act=1: elu. grid (N/64, J/64) x 256.
// ---------------------------------------------------------------------------
__launch_bounds__(256)
__global__ void k_gemm(const float* __restrict__ A, const u16* __restrict__ Whi,
                       const u16* __restrict__ Wlo, const float* __restrict__ b1,
                       const float* __restrict__ b2, float* __restrict__ outf,
                       int K, int J, int act) {
  const int l = threadIdx.x & 63;
  const int wv = threadIdx.x >> 6;
  const int l15 = l & 15, q = l >> 4;
  const int row0 = blockIdx.x * 64 + wv * 16;
  const int col0 = blockIdx.y * 64;
  const float* aptr = A + (size_t)(row0 + l15) * K;
  f4v acc[4];
#pragma unroll
  for (int i = 0; i < 4; ++i) acc[i] = (f4v){0.f, 0.f, 0.f, 0.f};
  const int nkt = K >> 5;
  for (int kt = 0; kt < nkt; ++kt) {
    int k0 = kt * 32 + q * 8;
    s8v ah, al;
    cvt8(aptr + k0, ah, al);
#pragma unroll
    for (int nt = 0; nt < 4; ++nt) {
      int j = col0 + nt * 16 + l15;
      s8v wh = load8bf(Whi + (size_t)j * K + k0);
      s8v wl = load8bf(Wlo + (size_t)j * K + k0);
      acc[nt] = mfma16(ah, wh, acc[nt]);
      acc[nt] = mfma16(al, wh, acc[nt]);
      acc[nt] = mfma16(ah, wl, acc[nt]);
    }
  }
#pragma unroll
  for (int nt = 0; nt < 4; ++nt) {
    int col = col0 + nt * 16 + l15;
    float bias = b1[col] + (b2 ? b2[col] : 0.f);
#pragma unroll
    for (int r = 0; r < 4; ++r) {
      int rr = row0 + q * 4 + r;
      float v = acc[nt][r] + bias;
      if (act) v = v > 0.f ? v : (__builtin_amdgcn_exp2f(v * 1.4426950408889634f) - 1.f);
      outf[(size_t)rr * J + col] = v;
    }
  }
}

// ---------------------------------------------------------------------------
// MFMA RNN scan v3: 16 workgroups, ONE PER BATCH ROW (independent
// recurrences -> no cross-wg traffic; spreads xw-read/out-write over 16 CUs).
// 256 threads = 4 waves; wave wv owns output cols [wv*64, wv*64+64).
// B-operand = Whh rows (pinned, w[4][8] = 128 VGPRs/thread).
// A-operand = h BROADCAST to all 16 M-rows (one same-address ds_read per kt)
// -> every C register is a valid copy; lane (q,l15) uses acc[nt][0] =
// D[j = wv*64+nt*16+l15]. Epilogue: 4 tanh/thread, quad-0 lanes store.
// Single LDS-only barrier per step; xw prefetched 2 steps ahead.
// ---------------------------------------------------------------------------
__launch_bounds__(256, 1)
__global__ void k_scan_m(const float* __restrict__ xw, const u16* __restrict__ Wb,
                         float* __restrict__ outf, const float* __restrict__ maskf) {
  __shared__ u16 H[2][272];
  __shared__ float mtab[512];
  const int tid = threadIdx.x;
  const int l = tid & 63, wv = tid >> 6;  // wv 0..3
  const int l15 = l & 15, q = l >> 4;
  const int b = blockIdx.x;  // batch row

  // stationary B fragments (Whh rows j), pinned into registers
  s8v w[4][8];
#pragma unroll
  for (int nt = 0; nt < 4; ++nt) {
    int j = wv * 64 + nt * 16 + l15;
#pragma unroll
    for (int kt = 0; kt < 8; ++kt)
      w[nt][kt] = pin8(load8bf(Wb + (j << 8) + kt * 32 + q * 8));
  }
  if (tid < 256) H[0][tid] = 0;  // h0 = 0 (image 0); image 1 fully written in step 0
  for (int c = tid; c < 512; c += 256)
    mtab[c] = maskf ? maskf[c * 16 + b] : 1.f;
  __syncthreads();

  const size_t nbase = (size_t)b << 9;          // n = b*512 + s
  const float* xrow = xw + (nbase << 8);
  const int j0 = wv * 64 + l15;                 // + nt*16
  const int q0 = (q == 0);

  float xA[4], xB[4];
#pragma unroll
  for (int nt = 0; nt < 4; ++nt) {
    xA[nt] = xrow[j0 + nt * 16];
    xB[nt] = xrow[256 + j0 + nt * 16];
  }

  auto STEP = [&](int s, int par, float* xc) {
    const u16* Hr = &H[par][0];
    f4v acc[4];
#pragma unroll
    for (int nt = 0; nt < 4; ++nt) acc[nt] = (f4v){xc[nt], 0.f, 0.f, 0.f};
#pragma unroll
    for (int kt = 0; kt < 8; ++kt) {
      s8v ha = load8bf(Hr + kt * 32 + q * 8);  // broadcast: same addr for all l15
#pragma unroll
      for (int nt = 0; nt < 4; ++nt) acc[nt] = mfma16(ha, w[nt][kt], acc[nt]);
    }
    float mf = mtab[s];
    u16* Hw = &H[1 - par][0];
    float* orow = outf + ((nbase + s) << 8);
#pragma unroll
    for (int nt = 0; nt < 4; ++nt) {
      float h = fast_tanh(acc[nt][0]);  // acc[nt][0] identical across quads
      if (q0) {
        Hw[j0 + nt * 16] = f2bf(h);
        orow[j0 + nt * 16] = h * mf;
      }
    }
  };

  for (int s = 0; s < 512; s += 2) {
    STEP(s, 0, xA);
    int sp = s + 2; if (sp > 511) sp = 511;
#pragma unroll
    for (int nt = 0; nt < 4; ++nt) xA[nt] = xrow[(sp << 8) + j0 + nt * 16];
    barrier_lds();
    STEP(s + 1, 1, xB);
    int sq = s + 3; if (sq > 511) sq = 511;
#pragma unroll
    for (int nt = 0; nt < 4; ++nt) xB[nt] = xrow[(sq << 8) + j0 + nt * 16];
    barrier_lds();
  }
}

// ---------------------------------------------------------------------------
// Encoder: 32 steps, 32 rows/wg, 512 threads = 8 waves; weights resident;
// h0/h1 bf16 in LDS.
// ---------------------------------------------------------------------------
__launch_bounds__(512, 2)
__global__ void k_enc(const float* __restrict__ gs,
                      const u16* __restrict__ W0b, const u16* __restrict__ W1b,
                      const u16* __restrict__ W2b, const float* __restrict__ wih0,
                      const float* __restrict__ bih0, const float* __restrict__ bhh0,
                      const float* __restrict__ bih1, const float* __restrict__ bhh1,
                      const float* __restrict__ clsW, const float* __restrict__ clsb,
                      float* __restrict__ Ab) {
  __shared__ __align__(16) u16 hA0[32 * 264];
  __shared__ __align__(16) u16 hA1[32 * 264];
  __shared__ float xe[32];
  __shared__ float b0v[256], w0v[256], b1v[256], clsv[256];
  __shared__ float clsbs;
  const int tid = threadIdx.x;
  const int n0 = blockIdx.x * 32;

  for (int c = tid; c < 8192; c += 512) {
    int row = c >> 8, col = c & 255;
    hA0[row * 264 + col] = f2bf(gs[(((size_t)(n0 + row)) << 8) + col]);
    hA1[row * 264 + col] = 0;
  }
  if (tid < 256) {
    b0v[tid] = bih0[tid] + bhh0[tid];
    w0v[tid] = wih0[tid];
    b1v[tid] = bih1[tid] + bhh1[tid];
    clsv[tid] = clsW[tid];
  }
  if (tid < 32) xe[tid] = 1.0f;
  if (tid == 0) clsbs = clsb[0];

  const int l = tid & 63, wv = tid >> 6;
  const int l15 = l & 15, q = l >> 4;
  const int colbase = wv * 32;

  s8v w0[2][8], w1[2][8], w2[2][8];
#pragma unroll
  for (int nt = 0; nt < 2; ++nt) {
    int jj = colbase + nt * 16 + l15;
#pragma unroll
    for (int kt = 0; kt < 8; ++kt) {
      int off = (jj << 8) + kt * 32 + q * 8;
      w0[nt][kt] = load8bf(W0b + off);
      w1[nt][kt] = load8bf(W1b + off);
      w2[nt][kt] = load8bf(W2b + off);
    }
  }
  __syncthreads();

  for (int m = 0; m < 32; ++m) {
    f4v acc[2][2];
#pragma unroll
    for (int mt = 0; mt < 2; ++mt)
#pragma unroll
      for (int nt = 0; nt < 2; ++nt) acc[mt][nt] = (f4v){0.f, 0.f, 0.f, 0.f};
#pragma unroll
    for (int kt = 0; kt < 8; ++kt) {
#pragma unroll
      for (int mt = 0; mt < 2; ++mt) {
        s8v a = __builtin_bit_cast(s8v, *(const uint4*)&hA0[(mt * 16 + l15) * 264 + kt * 32 + q * 8]);
        acc[mt][0] = mfma16(a, w0[0][kt], acc[mt][0]);
        acc[mt][1] = mfma16(a, w0[1][kt], acc[mt][1]);
      }
    }
    __syncthreads();
#pragma unroll
    for (int nt = 0; nt < 2; ++nt) {
      int col = colbase + nt * 16 + l15;
      float wc = w0v[col], bc = b0v[col];
#pragma unroll
      for (int mt = 0; mt < 2; ++mt)
#pragma unroll
        for (int r = 0; r < 4; ++r) {
          int row = mt * 16 + q * 4 + r;
          float v = acc[mt][nt][r] + xe[row] * wc + bc;
          hA0[row * 264 + col] = f2bf(fast_tanh(v));
        }
    }
    __syncthreads();
#pragma unroll
    for (int mt = 0; mt < 2; ++mt)
#pragma unroll
      for (int nt = 0; nt < 2; ++nt) acc[mt][nt] = (f4v){0.f, 0.f, 0.f, 0.f};
#pragma unroll
    for (int kt = 0; kt < 8; ++kt) {
#pragma unroll
      for (int mt = 0; mt < 2; ++mt) {
        s8v a0 = __builtin_bit_cast(s8v, *(const uint4*)&hA0[(mt * 16 + l15) * 264 + kt * 32 + q * 8]);
        s8v a1 = __builtin_bit_cast(s8v, *(const uint4*)&hA1[(mt * 16 + l15) * 264 + kt * 32 + q * 8]);
        acc[mt][0] = mfma16(a0, w1[0][kt], acc[mt][0]);
        acc[mt][1] = mfma16(a0, w1[1][kt], acc[mt][1]);
        acc[mt][0] = mfma16(a1, w2[0][kt], acc[mt][0]);
        acc[mt][1] = mfma16(a1, w2[1][kt], acc[mt][1]);
      }
    }
    __syncthreads();
#pragma unroll
    for (int nt = 0; nt < 2; ++nt) {
      int col = colbase + nt * 16 + l15;
      float bc = b1v[col];
#pragma unroll
      for (int mt = 0; mt < 2; ++mt)
#pragma unroll
        for (int r = 0; r < 4; ++r) {
          int row = mt * 16 + q * 4 + r;
          float v = acc[mt][nt][r] + bc;
          hA1[row * 264 + col] = f2bf(fast_tanh(v));
        }
    }
    __syncthreads();
    if (tid < 256) {
      int row = tid >> 3, seg = tid & 7;
      float sum = 0.f;
#pragma unroll
      for (int u = 0; u < 4; ++u) {
        int col = seg * 32 + u * 8;
#pragma unroll
        for (int e = 0; e < 8; ++e) sum += bf2f(hA1[row * 264 + col + e]) * clsv[col + e];
      }
      sum += __shfl_down(sum, 4, 8);
      sum += __shfl_down(sum, 2, 8);
      sum += __shfl_down(sum, 1, 8);
      if (seg == 0) {
        float pp = fast_sigmoid(sum + clsbs);
        xe[row] = pp;
        Ab[(((size_t)(n0 + row)) << 5) + m] = pp;
      }
    }
    __syncthreads();
  }
}

// ---------------------------------------------------------------------------
// arc_logits[b][j][i] = (j>=max(0,i-32) && j<i) ? Ab[(b*512+i)*32 + j-start] : 0
// ---------------------------------------------------------------------------
__global__ void k_arc(const float* __restrict__ Ab, float* __restrict__ out2) {
  int t = blockIdx.x * 256 + threadIdx.x;  // 4194304 total
  int b = t >> 18;
  int rem = t & 262143;
  int j = rem >> 9, i = rem & 511;
  int start = i - 32;
  if (start < 0) start = 0;
  float v = 0.f;
  if (j >= start && j < i) v = Ab[((((size_t)b << 9) + i) << 5) + (j - start)];
  out2[t] = v;
}

// ---------------------------------------------------------------------------
extern "C" void kernel_launch(void* const* d_in, const int* in_sizes, int n_in,
                              void* d_out, int out_size, void* d_ws, size_t ws_size,
                              hipStream_t stream) {
  const float* input    = (const float*)d_in[0];
  const float* sentinel = (const float*)d_in[1];
  const float* g_Wih0   = (const float*)d_in[2];
  const float* g_Whh0   = (const float*)d_in[3];
  const float* g_bih0   = (const float*)d_in[4];
  const float* g_bhh0   = (const float*)d_in[5];
  const float* g_Wih1   = (const float*)d_in[6];
  const float* g_Whh1   = (const float*)d_in[7];
  const float* g_bih1   = (const float*)d_in[8];
  const float* g_bhh1   = (const float*)d_in[9];
  const float* e_Wih0   = (const float*)d_in[10];
  const float* e_Whh0   = (const float*)d_in[11];
  const float* e_bih0   = (const float*)d_in[12];
  const float* e_bhh0   = (const float*)d_in[13];
  const float* e_Wih1   = (const float*)d_in[14];
  const float* e_Whh1   = (const float*)d_in[15];
  const float* e_bih1   = (const float*)d_in[16];
  const float* e_bhh1   = (const float*)d_in[17];
  const float* cls_W    = (const float*)d_in[18];
  const float* cls_b    = (const float*)d_in[19];
  const float* head_W   = (const float*)d_in[20];
  const float* head_b   = (const float*)d_in[21];
  const float* dep_W    = (const float*)d_in[22];
  const float* dep_b    = (const float*)d_in[23];
  const int* mask       = (const int*)d_in[24];

  float* out = (float*)d_out;
  char* ws = (char*)d_ws;
  float* xw_buf = (float*)ws;                                  // 8 MB
  float* hseq   = (float*)(ws + (8u << 20));                   // 8 MB
  float* gsb    = (float*)(ws + (16u << 20));                  // 8 MB
  float* Ab     = (float*)(ws + (24u << 20));                  // 1 MB
  size_t o = (25u << 20);
  u16* whh0b   = (u16*)(ws + o); o += 128u << 10;
  u16* whh1b   = (u16*)(ws + o); o += 128u << 10;
  float* maskfb= (float*)(ws + o); o += 32u << 10;
  u16* eb0     = (u16*)(ws + o); o += 128u << 10;
  u16* eb1     = (u16*)(ws + o); o += 128u << 10;
  u16* eb2     = (u16*)(ws + o); o += 128u << 10;
  u16* gw0hi   = (u16*)(ws + o); o += 256u << 10;
  u16* gw0lo   = (u16*)(ws + o); o += 256u << 10;
  u16* gw1hi   = (u16*)(ws + o); o += 128u << 10;
  u16* gw1lo   = (u16*)(ws + o); o += 128u << 10;
  u16* hWhi    = (u16*)(ws + o); o += 64u << 10;
  u16* hWlo    = (u16*)(ws + o); o += 64u << 10;
  u16* dWhi    = (u16*)(ws + o); o += 64u << 10;
  u16* dWlo    = (u16*)(ws + o); o += 64u << 10;

  k_prep<<<2336, 256, 0, stream>>>(g_Whh0, g_Whh1, whh0b, whh1b, e_Whh0, e_Wih1, e_Whh1,
                                   eb0, eb1, eb2, g_Wih0, gw0hi, gw0lo, g_Wih1, gw1hi,
                                   gw1lo, head_W, hWhi, hWlo, dep_W, dWhi, dWlo,
                                   mask, maskfb);
  k_xw0<<<dim3(128, 4), 256, 0, stream>>>(input, sentinel, gw0hi, gw0lo, g_bih0, g_bhh0,
                                          xw_buf);
  k_scan_m<<<16, 256, 0, stream>>>(xw_buf, whh0b, hseq, nullptr);
  k_gemm<<<dim3(128, 4), 256, 0, stream>>>(hseq, gw1hi, gw1lo, g_bih1, g_bhh1, xw_buf,
                                           256, 256, 0);
  k_scan_m<<<16, 256, 0, stream>>>(xw_buf, whh1b, gsb, maskfb);
  k_gemm<<<dim3(128, 2), 256, 0, stream>>>(gsb, hWhi, hWlo, head_b, nullptr, out,
                                           256, 128, 1);
  k_gemm<<<dim3(128, 2), 256, 0, stream>>>(gsb, dWhi, dWlo, dep_b, nullptr, out + 1048576,
                                           256, 128, 1);
  k_enc<<<256, 512, 0, stream>>>(gsb, eb0, eb1, eb2, e_Wih0, e_bih0, e_bhh0,
                                 e_bih1, e_bhh1, cls_W, cls_b, Ab);
  k_arc<<<16384, 256, 0, stream>>>(Ab, out + 2097152);
}